// Round 9
// baseline (274.965 us; speedup 1.0000x reference)
//
#include <hip/hip_runtime.h>
#include <math.h>

#define SUPPORT 1.5f
#define KS 8   // K-split factor for gemm

typedef float vf4 __attribute__((ext_vector_type(4)));
typedef float vf2 __attribute__((ext_vector_type(2)));

// ---------------- hat basis ----------------
__device__ __forceinline__ void hat4(float u, float h[4]) {
#pragma unroll
    for (int j = 0; j < 4; ++j) {
        float c = -1.0f + j * (2.0f / 3.0f);
        h[j] = fmaxf(0.0f, 1.0f - fabsf(u - c) * 1.5f);
    }
}

// ---------------- per-edge RBF coefficients ----------------
template <bool NEG>
__global__ void coeff_kernel(const float2* __restrict__ pa, const int* __restrict__ ia,
                             const float2* __restrict__ pb, const int* __restrict__ ib,
                             float* __restrict__ out, int E) {
    int e = blockIdx.x * blockDim.x + threadIdx.x;
    if (e >= E) return;
    float2 A = pa[ia[e]];
    float2 B = pb[ib[e]];
    float rx = (A.x - B.x) / SUPPORT;
    float ry = (A.y - B.y) / SUPPORT;
    if (NEG) { rx = -rx; ry = -ry; }
    float dx = fminf(fmaxf(rx, -1.0f), 1.0f);
    float dy = fminf(fmaxf(ry, -1.0f), 1.0f);
    float r  = sqrtf(dx * dx + dy * dy) * 2.0f - 1.0f;
    float th = atan2f(dy, dx) / 3.14159265358979323846f;
    float hr[4], ht[4];
    hat4(r, hr);
    hat4(th, ht);
    float* o = out + (size_t)e * 16;
#pragma unroll
    for (int a = 0; a < 4; ++a)
#pragma unroll
        for (int b = 0; b < 4; ++b)
            o[a * 4 + b] = hr[a] * ht[b];
}

// ---------------- CSR offsets ----------------
__global__ void offsets_kernel(const int* __restrict__ sorted, int E,
                               int* __restrict__ off, int N1) {
    int i = blockIdx.x * blockDim.x + threadIdx.x;
    if (i >= N1) return;
    int lo = 0, hi = E;
    while (lo < hi) {
        int mid = (lo + hi) >> 1;
        if (sorted[mid] < i) lo = mid + 1; else hi = mid;
    }
    off[i] = lo;
}

// ---------------- layer 1 (small Cin, direct) ----------------
__global__ void layer1_kernel(const float* __restrict__ fluidFeats,
                              const float* __restrict__ boundaryFeats,
                              const float* __restrict__ fcW0, const float* __restrict__ fcb0,
                              const float* __restrict__ W0, const float* __restrict__ b0,
                              const float* __restrict__ W1, const float* __restrict__ b1,
                              const float* __restrict__ W2, const float* __restrict__ b2,
                              const float* __restrict__ W3, const float* __restrict__ b3,
                              const int* __restrict__ f_off, const int* __restrict__ fe_j,
                              const float* __restrict__ f_coeff,
                              const int* __restrict__ b_off, const int* __restrict__ be_b,
                              const float* __restrict__ b_coeff,
                              float* __restrict__ A1) {
    int n = blockIdx.x;
    int t = threadIdx.x;
    if (t >= 96) return;
    float val;
    if (t < 32) {
        val = fluidFeats[n * 2] * fcW0[t] + fluidFeats[n * 2 + 1] * fcW0[32 + t] + fcb0[t];
    } else if (t < 64) {
        int oc = t - 32;
        const float* W = (oc < 16) ? W0 : W1;
        int o16 = oc & 15;
        float s = (oc < 16) ? b0[o16] : b1[o16];
        int e1 = f_off[n + 1];
        for (int e = f_off[n]; e < e1; ++e) {
            const float* cf = f_coeff + (size_t)e * 16;
            int srcn = fe_j[e];
            float f0 = fluidFeats[srcn * 2], f1 = fluidFeats[srcn * 2 + 1];
            float acc = 0.0f;
#pragma unroll
            for (int k = 0; k < 16; ++k)
                acc += cf[k] * (f0 * W[(k * 2 + 0) * 16 + o16] + f1 * W[(k * 2 + 1) * 16 + o16]);
            s += acc;
        }
        val = s;
    } else {
        int oc = t - 64;
        const float* W = (oc < 16) ? W2 : W3;
        int o16 = oc & 15;
        float s = (oc < 16) ? b2[o16] : b3[o16];
        int e1 = b_off[n + 1];
        for (int e = b_off[n]; e < e1; ++e) {
            const float* cf = b_coeff + (size_t)e * 16;
            int srcn = be_b[e];
            float f0 = boundaryFeats[srcn * 3], f1 = boundaryFeats[srcn * 3 + 1],
                  f2 = boundaryFeats[srcn * 3 + 2];
            float acc = 0.0f;
#pragma unroll
            for (int k = 0; k < 16; ++k)
                acc += cf[k] * (f0 * W[(k * 3 + 0) * 16 + o16] +
                                f1 * W[(k * 3 + 1) * 16 + o16] +
                                f2 * W[(k * 3 + 2) * 16 + o16]);
            s += acc;
        }
        val = s;
    }
    A1[(size_t)n * 96 + t] = fmaxf(val, 0.0f);
}

// ---------------- prep: k-major concatenated weight matrix ----------------
__global__ void prep_kernel(const float* __restrict__ WA, const float* __restrict__ WB,
                            const float* __restrict__ fcW, float* __restrict__ Wcat,
                            int CIN, int KTOT) {
    int idx = blockIdx.x * 256 + threadIdx.x;
    if (idx >= KTOT * 64) return;
    int j = idx >> 6, o = idx & 63;
    int KC = 16 * CIN;
    float v;
    if (j < KC) v = (o < 32) ? WA[(size_t)j * 32 + o] : WB[(size_t)j * 32 + (o - 32)];
    else        v = fcW[(size_t)(j - KC) * 64 + o];
    Wcat[idx] = v;
}

// ---------------- buildG: one wave per node; NT stores keep X in L2 ----------------
template <int CIN, bool RELU>
__global__ __launch_bounds__(256) void buildG_kernel(
    const float* __restrict__ X,
    const int* __restrict__ f_off, const int* __restrict__ fe_j,
    const float* __restrict__ f_coeff,
    float* __restrict__ G, int nodeBase, int totalCnt) {
    constexpr int EPT = CIN / 4;       // 24 (CIN=96) or 16 (CIN=64)
    constexpr int NV = EPT / 4;        // float4s per lane per edge: 6 or 4
    constexpr int KTOT = 17 * CIN;

    int wv   = threadIdx.x >> 6;
    int lane = threadIdx.x & 63;
    int ln   = blockIdx.x * 4 + wv;    // chunk-local node
    if (ln >= totalCnt) return;
    int n  = nodeBase + ln;
    int k  = lane >> 2;
    int i0 = (lane & 3) * EPT;

    float acc[EPT];
#pragma unroll
    for (int s = 0; s < EPT; ++s) acc[s] = 0.0f;

    int e0 = f_off[n], e1 = f_off[n + 1];
    for (int e = e0; e < e1; e += 2) {
        int ea = e;
        int eb = (e + 1 < e1) ? e + 1 : e;
        int s0 = __builtin_nontemporal_load(fe_j + ea);
        int s1 = __builtin_nontemporal_load(fe_j + eb);
        float c0 = __builtin_nontemporal_load(f_coeff + (size_t)ea * 16 + k);
        float c1 = __builtin_nontemporal_load(f_coeff + (size_t)eb * 16 + k);
        c1 = (e + 1 < e1) ? c1 : 0.0f;
        const float4* x0 = (const float4*)(X + (size_t)s0 * CIN + i0);
        const float4* x1 = (const float4*)(X + (size_t)s1 * CIN + i0);
        float4 v0[NV], v1[NV];
#pragma unroll
        for (int q = 0; q < NV; ++q) v0[q] = x0[q];
#pragma unroll
        for (int q = 0; q < NV; ++q) v1[q] = x1[q];
        if (RELU) {
#pragma unroll
            for (int q = 0; q < NV; ++q) {
                v0[q].x = fmaxf(v0[q].x, 0.f); v0[q].y = fmaxf(v0[q].y, 0.f);
                v0[q].z = fmaxf(v0[q].z, 0.f); v0[q].w = fmaxf(v0[q].w, 0.f);
                v1[q].x = fmaxf(v1[q].x, 0.f); v1[q].y = fmaxf(v1[q].y, 0.f);
                v1[q].z = fmaxf(v1[q].z, 0.f); v1[q].w = fmaxf(v1[q].w, 0.f);
            }
        }
#pragma unroll
        for (int q = 0; q < NV; ++q) {
            acc[4*q+0] = fmaf(c0, v0[q].x, acc[4*q+0]);
            acc[4*q+1] = fmaf(c0, v0[q].y, acc[4*q+1]);
            acc[4*q+2] = fmaf(c0, v0[q].z, acc[4*q+2]);
            acc[4*q+3] = fmaf(c0, v0[q].w, acc[4*q+3]);
            acc[4*q+0] = fmaf(c1, v1[q].x, acc[4*q+0]);
            acc[4*q+1] = fmaf(c1, v1[q].y, acc[4*q+1]);
            acc[4*q+2] = fmaf(c1, v1[q].z, acc[4*q+2]);
            acc[4*q+3] = fmaf(c1, v1[q].w, acc[4*q+3]);
        }
    }

    float* grow = G + (size_t)ln * KTOT;
    float* gp = grow + k * CIN + i0;
#pragma unroll
    for (int q = 0; q < NV; ++q) {
        vf4 o = {acc[4*q+0], acc[4*q+1], acc[4*q+2], acc[4*q+3]};
        __builtin_nontemporal_store(o, (vf4*)(gp + 4 * q));
    }
    // appended x_hat row for the fc term
    for (int i = lane; i < CIN; i += 64) {
        float v = X[(size_t)n * CIN + i];
        if (RELU) v = fmaxf(v, 0.0f);
        __builtin_nontemporal_store(v, grow + 16 * CIN + i);
    }
}

// ---------------- gemm: K-split partial GEMM, G & W tiles in LDS ----------------
template <int KTOT, int NSTEP>
__global__ __launch_bounds__(256) void gemm_kernel(
    const float* __restrict__ G,       // chunk-local rows, stride KTOT
    const float* __restrict__ Wcat,    // [KTOT][64] k-major
    float* __restrict__ P, int stride, int cnt) {
    __shared__ float Wl[68 * 64];
    __shared__ float Gl[32 * 72];
    const int t = threadIdx.x;
    const int tx = t & 31;
    const int ty = t >> 5;
    const int nb = blockIdx.x * 32;
    const int ks = blockIdx.y;
    int k0 = ks * (NSTEP * 68);

    float a00 = 0.f, a01 = 0.f, a10 = 0.f, a11 = 0.f;
    float a20 = 0.f, a21 = 0.f, a30 = 0.f, a31 = 0.f;

    for (int st = 0; st < NSTEP; ++st, k0 += 68) {
        __syncthreads();
        const float4* ws4 = (const float4*)(Wcat + (size_t)k0 * 64);
#pragma unroll
        for (int it = 0; it < 5; ++it) {
            int idx = it * 256 + t;
            if (idx < 1088) ((float4*)Wl)[idx] = ws4[idx];
        }
#pragma unroll
        for (int it = 0; it < 3; ++it) {
            int idx = it * 256 + t;
            if (idx < 544) {
                int n = idx / 17, off = idx - n * 17;
                int gn = nb + n;
                if (gn > cnt - 1) gn = cnt - 1;
                vf4 v = __builtin_nontemporal_load(
                    (const vf4*)(G + (size_t)gn * KTOT + k0 + off * 4));
                *(vf4*)(Gl + n * 72 + off * 4) = v;
            }
        }
        __syncthreads();

        const float* g0p = Gl + (4 * ty + 0) * 72;
        const float* g1p = Gl + (4 * ty + 1) * 72;
        const float* g2p = Gl + (4 * ty + 2) * 72;
        const float* g3p = Gl + (4 * ty + 3) * 72;
        const float* wp  = Wl + tx * 2;
#pragma unroll 2
        for (int kk = 0; kk < 68; kk += 4) {
            float4 g0 = *(const float4*)(g0p + kk);
            float4 g1 = *(const float4*)(g1p + kk);
            float4 g2 = *(const float4*)(g2p + kk);
            float4 g3 = *(const float4*)(g3p + kk);
#define GSTEP(u, comp)                                            \
            {                                                     \
                float2 w = *(const float2*)(wp + (kk + u) * 64);  \
                a00 = fmaf(g0.comp, w.x, a00);                    \
                a01 = fmaf(g0.comp, w.y, a01);                    \
                a10 = fmaf(g1.comp, w.x, a10);                    \
                a11 = fmaf(g1.comp, w.y, a11);                    \
                a20 = fmaf(g2.comp, w.x, a20);                    \
                a21 = fmaf(g2.comp, w.y, a21);                    \
                a30 = fmaf(g3.comp, w.x, a30);                    \
                a31 = fmaf(g3.comp, w.y, a31);                    \
            }
            GSTEP(0, x) GSTEP(1, y) GSTEP(2, z) GSTEP(3, w)
#undef GSTEP
        }
    }

    float* pb = P + ((size_t)ks * stride + nb) * 64 + tx * 2;
    int rem = cnt - nb;
#define PSTORE(nn, va, vb)                                                     \
    if (4 * ty + nn < rem) {                                                   \
        vf2 o = {va, vb};                                                      \
        __builtin_nontemporal_store(o, (vf2*)(pb + (4 * ty + nn) * 64));       \
    }
    PSTORE(0, a00, a01)
    PSTORE(1, a10, a11)
    PSTORE(2, a20, a21)
    PSTORE(3, a30, a31)
#undef PSTORE
}

// ---------------- reduce: sum K-split partials + bias (+resid) (*1/128) ----------------
template <bool RESID, bool FINAL>
__global__ void reduce_kernel(const float* __restrict__ P, int stride,
                              const float* __restrict__ bA, const float* __restrict__ bB,
                              const float* __restrict__ fcb,
                              const float* __restrict__ Xres,
                              float* __restrict__ OUT, int nodeBase, int cnt) {
    int idx = blockIdx.x * 256 + threadIdx.x;
    if (idx >= cnt * 64) return;
    int ln = idx >> 6, o = idx & 63;
    float s = ((o < 32) ? bA[o] : bB[o - 32]) + fcb[o];
#pragma unroll
    for (int ks = 0; ks < KS; ++ks)
        s += __builtin_nontemporal_load(P + ((size_t)ks * stride + ln) * 64 + o);
    int node = nodeBase + ln;
    if (RESID) s += Xres[(size_t)node * 64 + o];
    if (FINAL) s *= (1.0f / 128.0f);
    OUT[(size_t)node * 64 + o] = s;
}

// ---------------- fallback path (round-2 kernel, proven) ----------------
template <int CIN, bool RELU_IN, bool RESIDUAL, bool FINAL>
__global__ __launch_bounds__(256) void conv_layer_kernel(
    const float* __restrict__ X,
    const float* __restrict__ WA, const float* __restrict__ bA,
    const float* __restrict__ WB, const float* __restrict__ bB,
    const float* __restrict__ fcW, const float* __restrict__ fcb,
    const int* __restrict__ f_off, const int* __restrict__ fe_j,
    const float* __restrict__ f_coeff,
    float* __restrict__ OUT) {
    constexpr int NELEM = 16 * CIN;
    constexpr int EPT = NELEM / 256;
    constexpr int BATCH = 8;
    constexpr int CHUNK = NELEM / 4;

    __shared__ float x_lds[CIN];
    __shared__ float feat[BATCH][CIN];
    __shared__ float co[BATCH][16];
    __shared__ float Gs[NELEM];
    __shared__ float red[4][64];

    int n = blockIdx.x;
    int t = threadIdx.x;

    for (int i = t; i < CIN; i += 256) {
        float v = X[(size_t)n * CIN + i];
        if (RELU_IN) v = fmaxf(v, 0.0f);
        x_lds[i] = v;
    }

    float acc[EPT];
    int kk[EPT], ii[EPT];
#pragma unroll
    for (int s = 0; s < EPT; ++s) {
        acc[s] = 0.0f;
        int j = s * 256 + t;
        kk[s] = j / CIN;
        ii[s] = j - kk[s] * CIN;
    }

    int e0 = f_off[n], e1 = f_off[n + 1];
    for (int eb = e0; eb < e1; eb += BATCH) {
        int cnt = min(BATCH, e1 - eb);
        __syncthreads();
        for (int idx = t; idx < cnt * 16; idx += 256) {
            int b = idx >> 4, c = idx & 15;
            co[b][c] = f_coeff[(size_t)(eb + b) * 16 + c];
        }
        for (int idx = t; idx < cnt * CIN; idx += 256) {
            int b = idx / CIN, i = idx - b * CIN;
            int srcn = fe_j[eb + b];
            float v = X[(size_t)srcn * CIN + i];
            if (RELU_IN) v = fmaxf(v, 0.0f);
            feat[b][i] = v;
        }
        __syncthreads();
#pragma unroll
        for (int b = 0; b < BATCH; ++b) {
            if (b >= cnt) break;
#pragma unroll
            for (int s = 0; s < EPT; ++s) acc[s] += co[b][kk[s]] * feat[b][ii[s]];
        }
    }
    __syncthreads();
#pragma unroll
    for (int s = 0; s < EPT; ++s) Gs[s * 256 + t] = acc[s];
    __syncthreads();

    int o = t & 63;
    int chunk = t >> 6;
    const float* Wp = (o < 32) ? WA : WB;
    int oc = o & 31;
    int j0 = chunk * CHUNK;
    float p0 = 0.f, p1 = 0.f, p2 = 0.f, p3 = 0.f;
    for (int j = j0; j < j0 + CHUNK; j += 4) {
        p0 += Gs[j + 0] * Wp[(size_t)(j + 0) * 32 + oc];
        p1 += Gs[j + 1] * Wp[(size_t)(j + 1) * 32 + oc];
        p2 += Gs[j + 2] * Wp[(size_t)(j + 2) * 32 + oc];
        p3 += Gs[j + 3] * Wp[(size_t)(j + 3) * 32 + oc];
    }
    red[chunk][o] = ((p0 + p1) + (p2 + p3));
    __syncthreads();
    if (t < 64) {
        float s = red[0][o] + red[1][o] + red[2][o] + red[3][o];
        s += (o < 32) ? bA[oc] : bB[oc];
        float fcv = fcb[o];
        for (int i = 0; i < CIN; ++i) fcv += x_lds[i] * fcW[i * 64 + o];
        s += fcv;
        if (RESIDUAL) s += X[(size_t)n * 64 + o];
        if (FINAL) s *= (1.0f / 128.0f);
        OUT[(size_t)n * 64 + o] = s;
    }
}

extern "C" void kernel_launch(void* const* d_in, const int* in_sizes, int n_in,
                              void* d_out, int out_size, void* d_ws, size_t ws_size,
                              hipStream_t stream) {
    const float* fluidPos      = (const float*)d_in[0];
    const float* boundaryPos   = (const float*)d_in[1];
    const float* fluidFeats    = (const float*)d_in[2];
    const float* boundaryFeats = (const float*)d_in[3];
    const int* fe_i = (const int*)d_in[4];
    const int* fe_j = (const int*)d_in[5];
    const int* be_f = (const int*)d_in[6];
    const int* be_b = (const int*)d_in[7];
    const float* W[8];
    const float* bb[8];
    for (int c = 0; c < 8; ++c) {
        W[c]  = (const float*)d_in[8 + 2 * c];
        bb[c] = (const float*)d_in[9 + 2 * c];
    }
    const float* fcW0 = (const float*)d_in[24];
    const float* fcb0 = (const float*)d_in[25];
    const float* fcW1 = (const float*)d_in[26];
    const float* fcb1 = (const float*)d_in[27];
    const float* fcW2 = (const float*)d_in[28];
    const float* fcb2 = (const float*)d_in[29];

    int NF = in_sizes[0] / 2;
    int EF = in_sizes[4];
    int EB = in_sizes[6];

    // ---- workspace layout (floats); every segment 16B-aligned ----
    float* ws = (float*)d_ws;
    size_t p = 0;
    float* f_coeff = ws + p;  p += (size_t)EF * 16;
    float* b_coeff = ws + p;  p += (size_t)EB * 16;
    float* A1      = ws + p;  p += (size_t)NF * 96;
    float* ans2    = ws + p;  p += (size_t)NF * 64;
    int*   f_off   = (int*)(ws + p);  p += (size_t)((NF + 4) & ~3);
    int*   b_off   = (int*)(ws + p);  p += (size_t)((NF + 4) & ~3);
    float* Wc2     = ws + p;  p += 1632 * 64;   // [KTOT][64] k-major
    float* Wc3     = ws + p;  p += 1088 * 64;
    float* Gbuf    = ws + p;
    size_t gBase = p;

    long wsFloats = (long)(ws_size / 4);
    long avail = wsFloats - (long)gBase;
    int chunk2 = 0, chunk3 = 0;
    if (avail > 0) {
        long per2 = 1632 + KS * 64, per3 = 1088 + KS * 64;
        chunk2 = (int)((avail / per2 < (long)NF) ? avail / per2 : NF) & ~31;
        chunk3 = (int)((avail / per3 < (long)NF) ? avail / per3 : NF) & ~31;
    }
    bool bigPath = (chunk2 >= 32) && (chunk3 >= 32);

    // ---- shared prologue ----
    coeff_kernel<true><<<(EF + 255) / 256, 256, 0, stream>>>(
        (const float2*)fluidPos, fe_j, (const float2*)fluidPos, fe_i, f_coeff, EF);
    coeff_kernel<false><<<(EB + 255) / 256, 256, 0, stream>>>(
        (const float2*)boundaryPos, be_b, (const float2*)fluidPos, be_f, b_coeff, EB);
    offsets_kernel<<<(NF + 1 + 255) / 256, 256, 0, stream>>>(fe_i, EF, f_off, NF + 1);
    offsets_kernel<<<(NF + 1 + 255) / 256, 256, 0, stream>>>(be_f, EB, b_off, NF + 1);

    layer1_kernel<<<NF, 128, 0, stream>>>(fluidFeats, boundaryFeats, fcW0, fcb0,
                                          W[0], bb[0], W[1], bb[1], W[2], bb[2], W[3], bb[3],
                                          f_off, fe_j, f_coeff, b_off, be_b, b_coeff, A1);

    if (bigPath) {
        prep_kernel<<<(1632 * 64 + 255) / 256, 256, 0, stream>>>(W[4], W[5], fcW1, Wc2, 96, 1632);
        prep_kernel<<<(1088 * 64 + 255) / 256, 256, 0, stream>>>(W[6], W[7], fcW2, Wc3, 64, 1088);

        // layer 2: A1 (already relu'd) -> ans2
        {
            float* Pbuf = Gbuf + (size_t)chunk2 * 1632;
            for (int s = 0; s < NF; s += chunk2) {
                int cnt = (NF - s < chunk2) ? (NF - s) : chunk2;
                int nblocks = (cnt + 31) / 32;
                buildG_kernel<96, false><<<(cnt + 3) / 4, 256, 0, stream>>>(
                    A1, f_off, fe_j, f_coeff, Gbuf, s, cnt);
                gemm_kernel<1632, 3><<<dim3(nblocks, KS), 256, 0, stream>>>(
                    Gbuf, Wc2, Pbuf, chunk2, cnt);
                reduce_kernel<false, false><<<(cnt * 64 + 255) / 256, 256, 0, stream>>>(
                    Pbuf, chunk2, bb[4], bb[5], fcb1, nullptr, ans2, s, cnt);
            }
        }
        // layer 3: relu(ans2) -> d_out, +residual, /128
        {
            float* Pbuf = Gbuf + (size_t)chunk3 * 1088;
            for (int s = 0; s < NF; s += chunk3) {
                int cnt = (NF - s < chunk3) ? (NF - s) : chunk3;
                int nblocks = (cnt + 31) / 32;
                buildG_kernel<64, true><<<(cnt + 3) / 4, 256, 0, stream>>>(
                    ans2, f_off, fe_j, f_coeff, Gbuf, s, cnt);
                gemm_kernel<1088, 2><<<dim3(nblocks, KS), 256, 0, stream>>>(
                    Gbuf, Wc3, Pbuf, chunk3, cnt);
                reduce_kernel<true, true><<<(cnt * 64 + 255) / 256, 256, 0, stream>>>(
                    Pbuf, chunk3, bb[6], bb[7], fcb2, ans2, (float*)d_out, s, cnt);
            }
        }
    } else {
        conv_layer_kernel<96, false, false, false><<<NF, 256, 0, stream>>>(
            A1, W[4], bb[4], W[5], bb[5], fcW1, fcb1, f_off, fe_j, f_coeff, ans2);
        conv_layer_kernel<64, true, true, true><<<NF, 256, 0, stream>>>(
            ans2, W[6], bb[6], W[7], bb[7], fcW2, fcb2, f_off, fe_j, f_coeff, (float*)d_out);
    }
}

// Round 10
// 188.254 us; speedup vs baseline: 1.4606x; 1.4606x over previous
//
#include <hip/hip_runtime.h>
#include <math.h>

#define SUPPORT 1.5f
#define KS 8   // K-split factor for gemm

typedef unsigned short ushort_t;

__device__ __forceinline__ float bf2f(unsigned short h) {
    union { unsigned int u; float f; } c;
    c.u = ((unsigned int)h) << 16;
    return c.f;
}
__device__ __forceinline__ unsigned short f2bf(float f) {
    union { float f; unsigned int u; } c;
    c.f = f;
    unsigned int lsb = (c.u >> 16) & 1u;
    c.u += 0x7fffu + lsb;   // round-to-nearest-even
    return (unsigned short)(c.u >> 16);
}

// ---------------- hat basis ----------------
__device__ __forceinline__ void hat4(float u, float h[4]) {
#pragma unroll
    for (int j = 0; j < 4; ++j) {
        float c = -1.0f + j * (2.0f / 3.0f);
        h[j] = fmaxf(0.0f, 1.0f - fabsf(u - c) * 1.5f);
    }
}

// ---------------- per-edge RBF coefficients ----------------
template <bool NEG>
__global__ void coeff_kernel(const float2* __restrict__ pa, const int* __restrict__ ia,
                             const float2* __restrict__ pb, const int* __restrict__ ib,
                             float* __restrict__ out, int E) {
    int e = blockIdx.x * blockDim.x + threadIdx.x;
    if (e >= E) return;
    float2 A = pa[ia[e]];
    float2 B = pb[ib[e]];
    float rx = (A.x - B.x) / SUPPORT;
    float ry = (A.y - B.y) / SUPPORT;
    if (NEG) { rx = -rx; ry = -ry; }
    float dx = fminf(fmaxf(rx, -1.0f), 1.0f);
    float dy = fminf(fmaxf(ry, -1.0f), 1.0f);
    float r  = sqrtf(dx * dx + dy * dy) * 2.0f - 1.0f;
    float th = atan2f(dy, dx) / 3.14159265358979323846f;
    float hr[4], ht[4];
    hat4(r, hr);
    hat4(th, ht);
    float* o = out + (size_t)e * 16;
#pragma unroll
    for (int a = 0; a < 4; ++a)
#pragma unroll
        for (int b = 0; b < 4; ++b)
            o[a * 4 + b] = hr[a] * ht[b];
}

// ---------------- CSR offsets ----------------
__global__ void offsets_kernel(const int* __restrict__ sorted, int E,
                               int* __restrict__ off, int N1) {
    int i = blockIdx.x * blockDim.x + threadIdx.x;
    if (i >= N1) return;
    int lo = 0, hi = E;
    while (lo < hi) {
        int mid = (lo + hi) >> 1;
        if (sorted[mid] < i) lo = mid + 1; else hi = mid;
    }
    off[i] = lo;
}

// ---------------- layer 1 (small Cin, direct); writes bf16 A1 ----------------
__global__ void layer1_kernel(const float* __restrict__ fluidFeats,
                              const float* __restrict__ boundaryFeats,
                              const float* __restrict__ fcW0, const float* __restrict__ fcb0,
                              const float* __restrict__ W0, const float* __restrict__ b0,
                              const float* __restrict__ W1, const float* __restrict__ b1,
                              const float* __restrict__ W2, const float* __restrict__ b2,
                              const float* __restrict__ W3, const float* __restrict__ b3,
                              const int* __restrict__ f_off, const int* __restrict__ fe_j,
                              const float* __restrict__ f_coeff,
                              const int* __restrict__ b_off, const int* __restrict__ be_b,
                              const float* __restrict__ b_coeff,
                              ushort_t* __restrict__ A1b) {
    int n = blockIdx.x;
    int t = threadIdx.x;
    if (t >= 96) return;
    float val;
    if (t < 32) {
        val = fluidFeats[n * 2] * fcW0[t] + fluidFeats[n * 2 + 1] * fcW0[32 + t] + fcb0[t];
    } else if (t < 64) {
        int oc = t - 32;
        const float* W = (oc < 16) ? W0 : W1;
        int o16 = oc & 15;
        float s = (oc < 16) ? b0[o16] : b1[o16];
        int e1 = f_off[n + 1];
        for (int e = f_off[n]; e < e1; ++e) {
            const float* cf = f_coeff + (size_t)e * 16;
            int srcn = fe_j[e];
            float f0 = fluidFeats[srcn * 2], f1 = fluidFeats[srcn * 2 + 1];
            float acc = 0.0f;
#pragma unroll
            for (int k = 0; k < 16; ++k)
                acc += cf[k] * (f0 * W[(k * 2 + 0) * 16 + o16] + f1 * W[(k * 2 + 1) * 16 + o16]);
            s += acc;
        }
        val = s;
    } else {
        int oc = t - 64;
        const float* W = (oc < 16) ? W2 : W3;
        int o16 = oc & 15;
        float s = (oc < 16) ? b2[o16] : b3[o16];
        int e1 = b_off[n + 1];
        for (int e = b_off[n]; e < e1; ++e) {
            const float* cf = b_coeff + (size_t)e * 16;
            int srcn = be_b[e];
            float f0 = boundaryFeats[srcn * 3], f1 = boundaryFeats[srcn * 3 + 1],
                  f2 = boundaryFeats[srcn * 3 + 2];
            float acc = 0.0f;
#pragma unroll
            for (int k = 0; k < 16; ++k)
                acc += cf[k] * (f0 * W[(k * 3 + 0) * 16 + o16] +
                                f1 * W[(k * 3 + 1) * 16 + o16] +
                                f2 * W[(k * 3 + 2) * 16 + o16]);
            s += acc;
        }
        val = s;
    }
    A1b[(size_t)n * 96 + t] = f2bf(fmaxf(val, 0.0f));
}

// ---------------- prep: k-major concatenated weight matrix (fp32) ----------------
__global__ void prep_kernel(const float* __restrict__ WA, const float* __restrict__ WB,
                            const float* __restrict__ fcW, float* __restrict__ Wcat,
                            int CIN, int KTOT) {
    int idx = blockIdx.x * 256 + threadIdx.x;
    if (idx >= KTOT * 64) return;
    int j = idx >> 6, o = idx & 63;
    int KC = 16 * CIN;
    float v;
    if (j < KC) v = (o < 32) ? WA[(size_t)j * 32 + o] : WB[(size_t)j * 32 + (o - 32)];
    else        v = fcW[(size_t)(j - KC) * 64 + o];
    Wcat[idx] = v;
}

// ---------------- buildG: one wave per node; bf16 X in, bf16 G out ----------------
template <int CIN, bool RELU>
__global__ __launch_bounds__(256) void buildG_kernel(
    const ushort_t* __restrict__ Xb,   // [*, CIN] bf16
    const int* __restrict__ f_off, const int* __restrict__ fe_j,
    const float* __restrict__ f_coeff,
    ushort_t* __restrict__ Gb, int nodeBase, int totalCnt) {
    constexpr int EPT = CIN / 4;       // bf16 per lane: 24 (CIN=96) or 16 (CIN=64)
    constexpr int NU4 = EPT / 8;       // uint4 loads per lane per edge: 3 or 2
    constexpr int KTOT = 17 * CIN;

    int wv   = threadIdx.x >> 6;
    int lane = threadIdx.x & 63;
    int ln   = blockIdx.x * 4 + wv;
    if (ln >= totalCnt) return;
    int n  = nodeBase + ln;
    int k  = lane >> 2;
    int i0 = (lane & 3) * EPT;

    float acc[EPT];
#pragma unroll
    for (int s = 0; s < EPT; ++s) acc[s] = 0.0f;

    int e0 = f_off[n], e1 = f_off[n + 1];
    for (int e = e0; e < e1; e += 2) {
        int ea = e;
        int eb = (e + 1 < e1) ? e + 1 : e;
        int s0 = fe_j[ea], s1 = fe_j[eb];
        float c0 = f_coeff[(size_t)ea * 16 + k];
        float c1 = f_coeff[(size_t)eb * 16 + k];
        c1 = (e + 1 < e1) ? c1 : 0.0f;
        const uint4* x0 = (const uint4*)(Xb + (size_t)s0 * CIN + i0);
        const uint4* x1 = (const uint4*)(Xb + (size_t)s1 * CIN + i0);
        uint4 r0[NU4], r1[NU4];
#pragma unroll
        for (int q = 0; q < NU4; ++q) r0[q] = x0[q];
#pragma unroll
        for (int q = 0; q < NU4; ++q) r1[q] = x1[q];
#pragma unroll
        for (int q = 0; q < NU4; ++q) {
            unsigned int w0[4] = {r0[q].x, r0[q].y, r0[q].z, r0[q].w};
            unsigned int w1[4] = {r1[q].x, r1[q].y, r1[q].z, r1[q].w};
#pragma unroll
            for (int j = 0; j < 4; ++j) {
                float a0 = bf2f((unsigned short)(w0[j] & 0xffff));
                float b0v = bf2f((unsigned short)(w0[j] >> 16));
                float a1 = bf2f((unsigned short)(w1[j] & 0xffff));
                float b1v = bf2f((unsigned short)(w1[j] >> 16));
                if (RELU) {
                    a0 = fmaxf(a0, 0.f); b0v = fmaxf(b0v, 0.f);
                    a1 = fmaxf(a1, 0.f); b1v = fmaxf(b1v, 0.f);
                }
                int s = q * 8 + j * 2;
                acc[s + 0] = fmaf(c0, a0, acc[s + 0]);
                acc[s + 1] = fmaf(c0, b0v, acc[s + 1]);
                acc[s + 0] = fmaf(c1, a1, acc[s + 0]);
                acc[s + 1] = fmaf(c1, b1v, acc[s + 1]);
            }
        }
    }

    ushort_t* grow = Gb + (size_t)ln * KTOT;
    ushort_t* gp = grow + k * CIN + i0;
#pragma unroll
    for (int q = 0; q < NU4; ++q) {
        uint4 o;
        o.x = (unsigned int)f2bf(acc[q*8+0]) | ((unsigned int)f2bf(acc[q*8+1]) << 16);
        o.y = (unsigned int)f2bf(acc[q*8+2]) | ((unsigned int)f2bf(acc[q*8+3]) << 16);
        o.z = (unsigned int)f2bf(acc[q*8+4]) | ((unsigned int)f2bf(acc[q*8+5]) << 16);
        o.w = (unsigned int)f2bf(acc[q*8+6]) | ((unsigned int)f2bf(acc[q*8+7]) << 16);
        *(uint4*)(gp + q * 8) = o;
    }
    // appended x_hat row (bf16 copy, relu'd)
    for (int i = lane; i < CIN; i += 64) {
        ushort_t v = Xb[(size_t)n * CIN + i];
        if (RELU && (v & 0x8000)) v = 0;
        grow[16 * CIN + i] = v;
    }
}

// ---------------- gemm: K-split partial GEMM; bf16 G staged->fp32 LDS ----------------
template <int KTOT, int NSTEP>
__global__ __launch_bounds__(256) void gemm_kernel(
    const ushort_t* __restrict__ Gb,   // chunk-local rows, stride KTOT (bf16)
    const float* __restrict__ Wcat,    // [KTOT][64] k-major fp32
    float* __restrict__ P, int stride, int cnt) {
    __shared__ float Wl[68 * 64];
    __shared__ float Gl[32 * 72];
    const int t = threadIdx.x;
    const int tx = t & 31;
    const int ty = t >> 5;
    const int nb = blockIdx.x * 32;
    const int ks = blockIdx.y;
    int k0 = ks * (NSTEP * 68);

    float a00 = 0.f, a01 = 0.f, a10 = 0.f, a11 = 0.f;
    float a20 = 0.f, a21 = 0.f, a30 = 0.f, a31 = 0.f;

    for (int st = 0; st < NSTEP; ++st, k0 += 68) {
        __syncthreads();
        const float4* ws4 = (const float4*)(Wcat + (size_t)k0 * 64);
#pragma unroll
        for (int it = 0; it < 5; ++it) {
            int idx = it * 256 + t;
            if (idx < 1088) ((float4*)Wl)[idx] = ws4[idx];
        }
#pragma unroll
        for (int it = 0; it < 3; ++it) {
            int idx = it * 256 + t;
            if (idx < 544) {
                int n = idx / 17, off = idx - n * 17;
                int gn = nb + n;
                if (gn > cnt - 1) gn = cnt - 1;
                uint2 raw = *(const uint2*)(Gb + (size_t)gn * KTOT + k0 + off * 4);
                float4 v;
                v.x = bf2f((unsigned short)(raw.x & 0xffff));
                v.y = bf2f((unsigned short)(raw.x >> 16));
                v.z = bf2f((unsigned short)(raw.y & 0xffff));
                v.w = bf2f((unsigned short)(raw.y >> 16));
                *(float4*)(Gl + n * 72 + off * 4) = v;
            }
        }
        __syncthreads();

        const float* g0p = Gl + (4 * ty + 0) * 72;
        const float* g1p = Gl + (4 * ty + 1) * 72;
        const float* g2p = Gl + (4 * ty + 2) * 72;
        const float* g3p = Gl + (4 * ty + 3) * 72;
        const float* wp  = Wl + tx * 2;
#pragma unroll 2
        for (int kk = 0; kk < 68; kk += 4) {
            float4 g0 = *(const float4*)(g0p + kk);
            float4 g1 = *(const float4*)(g1p + kk);
            float4 g2 = *(const float4*)(g2p + kk);
            float4 g3 = *(const float4*)(g3p + kk);
#define GSTEP(u, comp)                                            \
            {                                                     \
                float2 w = *(const float2*)(wp + (kk + u) * 64);  \
                a00 = fmaf(g0.comp, w.x, a00);                    \
                a01 = fmaf(g0.comp, w.y, a01);                    \
                a10 = fmaf(g1.comp, w.x, a10);                    \
                a11 = fmaf(g1.comp, w.y, a11);                    \
                a20 = fmaf(g2.comp, w.x, a20);                    \
                a21 = fmaf(g2.comp, w.y, a21);                    \
                a30 = fmaf(g3.comp, w.x, a30);                    \
                a31 = fmaf(g3.comp, w.y, a31);                    \
            }
            GSTEP(0, x) GSTEP(1, y) GSTEP(2, z) GSTEP(3, w)
#undef GSTEP
        }
    }

    float* pb = P + ((size_t)ks * stride + nb) * 64 + tx * 2;
    int rem = cnt - nb;
    if (4 * ty + 0 < rem) *(float2*)(pb + (4 * ty + 0) * 64) = make_float2(a00, a01);
    if (4 * ty + 1 < rem) *(float2*)(pb + (4 * ty + 1) * 64) = make_float2(a10, a11);
    if (4 * ty + 2 < rem) *(float2*)(pb + (4 * ty + 2) * 64) = make_float2(a20, a21);
    if (4 * ty + 3 < rem) *(float2*)(pb + (4 * ty + 3) * 64) = make_float2(a30, a31);
}

// ---------------- reduce: sum partials + bias (+bf16 resid) -> bf16 or fp32 ----------------
template <bool RESID, bool FINAL, bool OUTBF>
__global__ void reduce_kernel(const float* __restrict__ P, int stride,
                              const float* __restrict__ bA, const float* __restrict__ bB,
                              const float* __restrict__ fcb,
                              const ushort_t* __restrict__ XresB,
                              void* __restrict__ OUT, int nodeBase, int cnt) {
    int idx = blockIdx.x * 256 + threadIdx.x;
    if (idx >= cnt * 64) return;
    int ln = idx >> 6, o = idx & 63;
    float s = ((o < 32) ? bA[o] : bB[o - 32]) + fcb[o];
#pragma unroll
    for (int ks = 0; ks < KS; ++ks) s += P[((size_t)ks * stride + ln) * 64 + o];
    int node = nodeBase + ln;
    if (RESID) s += bf2f(XresB[(size_t)node * 64 + o]);
    if (FINAL) s *= (1.0f / 128.0f);
    if (OUTBF) ((ushort_t*)OUT)[(size_t)node * 64 + o] = f2bf(s);
    else       ((float*)OUT)[(size_t)node * 64 + o] = s;
}

// ---------------- fallback path (bf16 X variant of proven round-2 kernel) ----------------
template <int CIN, bool RELU_IN, bool RESIDUAL, bool FINAL, bool OUTBF>
__global__ __launch_bounds__(256) void conv_layer_kernel(
    const ushort_t* __restrict__ Xb,
    const float* __restrict__ WA, const float* __restrict__ bA,
    const float* __restrict__ WB, const float* __restrict__ bB,
    const float* __restrict__ fcW, const float* __restrict__ fcb,
    const int* __restrict__ f_off, const int* __restrict__ fe_j,
    const float* __restrict__ f_coeff,
    void* __restrict__ OUT) {
    constexpr int NELEM = 16 * CIN;
    constexpr int EPT = NELEM / 256;
    constexpr int BATCH = 8;
    constexpr int CHUNK = NELEM / 4;

    __shared__ float x_lds[CIN];
    __shared__ float feat[BATCH][CIN];
    __shared__ float co[BATCH][16];
    __shared__ float Gs[NELEM];
    __shared__ float red[4][64];

    int n = blockIdx.x;
    int t = threadIdx.x;

    for (int i = t; i < CIN; i += 256) {
        float v = bf2f(Xb[(size_t)n * CIN + i]);
        if (RELU_IN) v = fmaxf(v, 0.0f);
        x_lds[i] = v;
    }

    float acc[EPT];
    int kk[EPT], ii[EPT];
#pragma unroll
    for (int s = 0; s < EPT; ++s) {
        acc[s] = 0.0f;
        int j = s * 256 + t;
        kk[s] = j / CIN;
        ii[s] = j - kk[s] * CIN;
    }

    int e0 = f_off[n], e1 = f_off[n + 1];
    for (int eb = e0; eb < e1; eb += BATCH) {
        int cnt = min(BATCH, e1 - eb);
        __syncthreads();
        for (int idx = t; idx < cnt * 16; idx += 256) {
            int b = idx >> 4, c = idx & 15;
            co[b][c] = f_coeff[(size_t)(eb + b) * 16 + c];
        }
        for (int idx = t; idx < cnt * CIN; idx += 256) {
            int b = idx / CIN, i = idx - b * CIN;
            int srcn = fe_j[eb + b];
            float v = bf2f(Xb[(size_t)srcn * CIN + i]);
            if (RELU_IN) v = fmaxf(v, 0.0f);
            feat[b][i] = v;
        }
        __syncthreads();
#pragma unroll
        for (int b = 0; b < BATCH; ++b) {
            if (b >= cnt) break;
#pragma unroll
            for (int s = 0; s < EPT; ++s) acc[s] += co[b][kk[s]] * feat[b][ii[s]];
        }
    }
    __syncthreads();
#pragma unroll
    for (int s = 0; s < EPT; ++s) Gs[s * 256 + t] = acc[s];
    __syncthreads();

    int o = t & 63;
    int chunk = t >> 6;
    const float* Wp = (o < 32) ? WA : WB;
    int oc = o & 31;
    int j0 = chunk * CHUNK;
    float p0 = 0.f, p1 = 0.f, p2 = 0.f, p3 = 0.f;
    for (int j = j0; j < j0 + CHUNK; j += 4) {
        p0 += Gs[j + 0] * Wp[(size_t)(j + 0) * 32 + oc];
        p1 += Gs[j + 1] * Wp[(size_t)(j + 1) * 32 + oc];
        p2 += Gs[j + 2] * Wp[(size_t)(j + 2) * 32 + oc];
        p3 += Gs[j + 3] * Wp[(size_t)(j + 3) * 32 + oc];
    }
    red[chunk][o] = ((p0 + p1) + (p2 + p3));
    __syncthreads();
    if (t < 64) {
        float s = red[0][o] + red[1][o] + red[2][o] + red[3][o];
        s += (o < 32) ? bA[oc] : bB[oc];
        float fcv = fcb[o];
        for (int i = 0; i < CIN; ++i) fcv += x_lds[i] * fcW[i * 64 + o];
        s += fcv;
        if (RESIDUAL) s += bf2f(Xb[(size_t)n * 64 + o]);
        if (FINAL) s *= (1.0f / 128.0f);
        if (OUTBF) ((ushort_t*)OUT)[(size_t)n * 64 + o] = f2bf(s);
        else       ((float*)OUT)[(size_t)n * 64 + o] = s;
    }
}

extern "C" void kernel_launch(void* const* d_in, const int* in_sizes, int n_in,
                              void* d_out, int out_size, void* d_ws, size_t ws_size,
                              hipStream_t stream) {
    const float* fluidPos      = (const float*)d_in[0];
    const float* boundaryPos   = (const float*)d_in[1];
    const float* fluidFeats    = (const float*)d_in[2];
    const float* boundaryFeats = (const float*)d_in[3];
    const int* fe_i = (const int*)d_in[4];
    const int* fe_j = (const int*)d_in[5];
    const int* be_f = (const int*)d_in[6];
    const int* be_b = (const int*)d_in[7];
    const float* W[8];
    const float* bb[8];
    for (int c = 0; c < 8; ++c) {
        W[c]  = (const float*)d_in[8 + 2 * c];
        bb[c] = (const float*)d_in[9 + 2 * c];
    }
    const float* fcW0 = (const float*)d_in[24];
    const float* fcb0 = (const float*)d_in[25];
    const float* fcW1 = (const float*)d_in[26];
    const float* fcb1 = (const float*)d_in[27];
    const float* fcW2 = (const float*)d_in[28];
    const float* fcb2 = (const float*)d_in[29];

    int NF = in_sizes[0] / 2;
    int EF = in_sizes[4];
    int EB = in_sizes[6];

    // ---- workspace layout (f32 units; all segments multiples of 4 -> 16B aligned) ----
    float* ws = (float*)d_ws;
    size_t p = 0;
    float* f_coeff = ws + p;  p += (size_t)EF * 16;
    float* b_coeff = ws + p;  p += (size_t)EB * 16;
    ushort_t* A1b  = (ushort_t*)(ws + p);  p += (size_t)NF * 48;   // NF*96 bf16
    ushort_t* ans2b= (ushort_t*)(ws + p);  p += (size_t)NF * 32;   // NF*64 bf16
    int*   f_off   = (int*)(ws + p);  p += (size_t)((NF + 4) & ~3);
    int*   b_off   = (int*)(ws + p);  p += (size_t)((NF + 4) & ~3);
    float* Wc2     = ws + p;  p += 1632 * 64;   // [KTOT][64] k-major fp32
    float* Wc3     = ws + p;  p += 1088 * 64;
    float* Gregion = ws + p;
    size_t gBase = p;

    long wsFloats = (long)(ws_size / 4);
    long avail = wsFloats - (long)gBase;
    int chunk2 = 0, chunk3 = 0;
    if (avail > 0) {
        long per2 = 1632 / 2 + KS * 64, per3 = 1088 / 2 + KS * 64;  // bf16 G + fp32 P
        chunk2 = (int)((avail / per2 < (long)NF) ? avail / per2 : NF) & ~31;
        chunk3 = (int)((avail / per3 < (long)NF) ? avail / per3 : NF) & ~31;
    }
    bool bigPath = (chunk2 >= 32) && (chunk3 >= 32);

    // ---- shared prologue ----
    coeff_kernel<true><<<(EF + 255) / 256, 256, 0, stream>>>(
        (const float2*)fluidPos, fe_j, (const float2*)fluidPos, fe_i, f_coeff, EF);
    coeff_kernel<false><<<(EB + 255) / 256, 256, 0, stream>>>(
        (const float2*)boundaryPos, be_b, (const float2*)fluidPos, be_f, b_coeff, EB);
    offsets_kernel<<<(NF + 1 + 255) / 256, 256, 0, stream>>>(fe_i, EF, f_off, NF + 1);
    offsets_kernel<<<(NF + 1 + 255) / 256, 256, 0, stream>>>(be_f, EB, b_off, NF + 1);

    layer1_kernel<<<NF, 128, 0, stream>>>(fluidFeats, boundaryFeats, fcW0, fcb0,
                                          W[0], bb[0], W[1], bb[1], W[2], bb[2], W[3], bb[3],
                                          f_off, fe_j, f_coeff, b_off, be_b, b_coeff, A1b);

    if (bigPath) {
        prep_kernel<<<(1632 * 64 + 255) / 256, 256, 0, stream>>>(W[4], W[5], fcW1, Wc2, 96, 1632);
        prep_kernel<<<(1088 * 64 + 255) / 256, 256, 0, stream>>>(W[6], W[7], fcW2, Wc3, 64, 1088);

        // layer 2: A1b (relu'd bf16) -> ans2b (bf16)
        {
            ushort_t* Gb = (ushort_t*)Gregion;
            float* Pbuf = Gregion + (size_t)chunk2 * (1632 / 2);
            for (int s = 0; s < NF; s += chunk2) {
                int cnt = (NF - s < chunk2) ? (NF - s) : chunk2;
                int nblocks = (cnt + 31) / 32;
                buildG_kernel<96, false><<<(cnt + 3) / 4, 256, 0, stream>>>(
                    A1b, f_off, fe_j, f_coeff, Gb, s, cnt);
                gemm_kernel<1632, 3><<<dim3(nblocks, KS), 256, 0, stream>>>(
                    Gb, Wc2, Pbuf, chunk2, cnt);
                reduce_kernel<false, false, true><<<(cnt * 64 + 255) / 256, 256, 0, stream>>>(
                    Pbuf, chunk2, bb[4], bb[5], fcb1, nullptr, ans2b, s, cnt);
            }
        }
        // layer 3: relu(ans2b) -> d_out (fp32), +bf16 residual, /128
        {
            ushort_t* Gb = (ushort_t*)Gregion;
            float* Pbuf = Gregion + (size_t)chunk3 * (1088 / 2);
            for (int s = 0; s < NF; s += chunk3) {
                int cnt = (NF - s < chunk3) ? (NF - s) : chunk3;
                int nblocks = (cnt + 31) / 32;
                buildG_kernel<64, true><<<(cnt + 3) / 4, 256, 0, stream>>>(
                    ans2b, f_off, fe_j, f_coeff, Gb, s, cnt);
                gemm_kernel<1088, 2><<<dim3(nblocks, KS), 256, 0, stream>>>(
                    Gb, Wc3, Pbuf, chunk3, cnt);
                reduce_kernel<true, true, false><<<(cnt * 64 + 255) / 256, 256, 0, stream>>>(
                    Pbuf, chunk3, bb[6], bb[7], fcb2, ans2b, d_out, s, cnt);
            }
        }
    } else {
        conv_layer_kernel<96, false, false, false, true><<<NF, 256, 0, stream>>>(
            A1b, W[4], bb[4], W[5], bb[5], fcW1, fcb1, f_off, fe_j, f_coeff, ans2b);
        conv_layer_kernel<64, true, true, true, false><<<NF, 256, 0, stream>>>(
            ans2b, W[6], bb[6], W[7], bb[7], fcW2, fcb2, f_off, fe_j, f_coeff, d_out);
    }
}

// Round 11
// 181.066 us; speedup vs baseline: 1.5186x; 1.0397x over previous
//
#include <hip/hip_runtime.h>
#include <math.h>

#define SUPPORT 1.5f
#define KS 8   // K-split factor for gemm

typedef unsigned short ushort_t;

__device__ __forceinline__ float bf2f(unsigned short h) {
    union { unsigned int u; float f; } c;
    c.u = ((unsigned int)h) << 16;
    return c.f;
}
__device__ __forceinline__ unsigned short f2bf(float f) {
    union { float f; unsigned int u; } c;
    c.f = f;
    unsigned int lsb = (c.u >> 16) & 1u;
    c.u += 0x7fffu + lsb;   // round-to-nearest-even
    return (unsigned short)(c.u >> 16);
}

// ---------------- hat basis ----------------
__device__ __forceinline__ void hat4(float u, float h[4]) {
#pragma unroll
    for (int j = 0; j < 4; ++j) {
        float c = -1.0f + j * (2.0f / 3.0f);
        h[j] = fmaxf(0.0f, 1.0f - fabsf(u - c) * 1.5f);
    }
}

// ---------------- per-edge RBF coefficients ----------------
template <bool NEG>
__global__ void coeff_kernel(const float2* __restrict__ pa, const int* __restrict__ ia,
                             const float2* __restrict__ pb, const int* __restrict__ ib,
                             float* __restrict__ out, int E) {
    int e = blockIdx.x * blockDim.x + threadIdx.x;
    if (e >= E) return;
    float2 A = pa[ia[e]];
    float2 B = pb[ib[e]];
    float rx = (A.x - B.x) / SUPPORT;
    float ry = (A.y - B.y) / SUPPORT;
    if (NEG) { rx = -rx; ry = -ry; }
    float dx = fminf(fmaxf(rx, -1.0f), 1.0f);
    float dy = fminf(fmaxf(ry, -1.0f), 1.0f);
    float r  = sqrtf(dx * dx + dy * dy) * 2.0f - 1.0f;
    float th = atan2f(dy, dx) / 3.14159265358979323846f;
    float hr[4], ht[4];
    hat4(r, hr);
    hat4(th, ht);
    float* o = out + (size_t)e * 16;
#pragma unroll
    for (int a = 0; a < 4; ++a)
#pragma unroll
        for (int b = 0; b < 4; ++b)
            o[a * 4 + b] = hr[a] * ht[b];
}

// ---------------- CSR offsets ----------------
__global__ void offsets_kernel(const int* __restrict__ sorted, int E,
                               int* __restrict__ off, int N1) {
    int i = blockIdx.x * blockDim.x + threadIdx.x;
    if (i >= N1) return;
    int lo = 0, hi = E;
    while (lo < hi) {
        int mid = (lo + hi) >> 1;
        if (sorted[mid] < i) lo = mid + 1; else hi = mid;
    }
    off[i] = lo;
}

// ---------------- layer 1 (small Cin, direct); W columns hoisted to registers ----------------
__global__ void layer1_kernel(const float* __restrict__ fluidFeats,
                              const float* __restrict__ boundaryFeats,
                              const float* __restrict__ fcW0, const float* __restrict__ fcb0,
                              const float* __restrict__ W0, const float* __restrict__ b0,
                              const float* __restrict__ W1, const float* __restrict__ b1,
                              const float* __restrict__ W2, const float* __restrict__ b2,
                              const float* __restrict__ W3, const float* __restrict__ b3,
                              const int* __restrict__ f_off, const int* __restrict__ fe_j,
                              const float* __restrict__ f_coeff,
                              const int* __restrict__ b_off, const int* __restrict__ be_b,
                              const float* __restrict__ b_coeff,
                              ushort_t* __restrict__ A1b) {
    int n = blockIdx.x;
    int t = threadIdx.x;
    if (t >= 96) return;
    float val;
    if (t < 32) {
        val = fluidFeats[n * 2] * fcW0[t] + fluidFeats[n * 2 + 1] * fcW0[32 + t] + fcb0[t];
    } else if (t < 64) {
        int oc = t - 32;
        const float* W = (oc < 16) ? W0 : W1;
        int o16 = oc & 15;
        float wk[32];
#pragma unroll
        for (int k = 0; k < 16; ++k) {
            wk[2 * k + 0] = W[(k * 2 + 0) * 16 + o16];
            wk[2 * k + 1] = W[(k * 2 + 1) * 16 + o16];
        }
        float s = (oc < 16) ? b0[o16] : b1[o16];
        int e1 = f_off[n + 1];
        for (int e = f_off[n]; e < e1; ++e) {
            const float* cf = f_coeff + (size_t)e * 16;
            int srcn = fe_j[e];
            float f0 = fluidFeats[srcn * 2], f1 = fluidFeats[srcn * 2 + 1];
            float acc = 0.0f;
#pragma unroll
            for (int k = 0; k < 16; ++k)
                acc += cf[k] * (f0 * wk[2 * k] + f1 * wk[2 * k + 1]);
            s += acc;
        }
        val = s;
    } else {
        int oc = t - 64;
        const float* W = (oc < 16) ? W2 : W3;
        int o16 = oc & 15;
        float wk[48];
#pragma unroll
        for (int k = 0; k < 16; ++k) {
            wk[3 * k + 0] = W[(k * 3 + 0) * 16 + o16];
            wk[3 * k + 1] = W[(k * 3 + 1) * 16 + o16];
            wk[3 * k + 2] = W[(k * 3 + 2) * 16 + o16];
        }
        float s = (oc < 16) ? b2[o16] : b3[o16];
        int e1 = b_off[n + 1];
        for (int e = b_off[n]; e < e1; ++e) {
            const float* cf = b_coeff + (size_t)e * 16;
            int srcn = be_b[e];
            float f0 = boundaryFeats[srcn * 3], f1 = boundaryFeats[srcn * 3 + 1],
                  f2 = boundaryFeats[srcn * 3 + 2];
            float acc = 0.0f;
#pragma unroll
            for (int k = 0; k < 16; ++k)
                acc += cf[k] * (f0 * wk[3 * k] + f1 * wk[3 * k + 1] + f2 * wk[3 * k + 2]);
            s += acc;
        }
        val = s;
    }
    A1b[(size_t)n * 96 + t] = f2bf(fmaxf(val, 0.0f));
}

// ---------------- prep: k-major concatenated weight matrix (fp32) ----------------
__global__ void prep_kernel(const float* __restrict__ WA, const float* __restrict__ WB,
                            const float* __restrict__ fcW, float* __restrict__ Wcat,
                            int CIN, int KTOT) {
    int idx = blockIdx.x * 256 + threadIdx.x;
    if (idx >= KTOT * 64) return;
    int j = idx >> 6, o = idx & 63;
    int KC = 16 * CIN;
    float v;
    if (j < KC) v = (o < 32) ? WA[(size_t)j * 32 + o] : WB[(size_t)j * 32 + (o - 32)];
    else        v = fcW[(size_t)(j - KC) * 64 + o];
    Wcat[idx] = v;
}

// ---------------- buildG: one wave per node; 4-wide edge unroll; bf16 in/out ----------------
template <int CIN, bool RELU>
__global__ __launch_bounds__(256) void buildG_kernel(
    const ushort_t* __restrict__ Xb,   // [*, CIN] bf16
    const int* __restrict__ f_off, const int* __restrict__ fe_j,
    const float* __restrict__ f_coeff,
    ushort_t* __restrict__ Gb, int nodeBase, int totalCnt) {
    constexpr int EPT = CIN / 4;       // bf16 per lane: 24 (CIN=96) or 16 (CIN=64)
    constexpr int NU4 = EPT / 8;       // uint4 loads per lane per edge: 3 or 2
    constexpr int KTOT = 17 * CIN;

    int wv   = threadIdx.x >> 6;
    int lane = threadIdx.x & 63;
    int ln   = blockIdx.x * 4 + wv;
    if (ln >= totalCnt) return;
    int n  = nodeBase + ln;
    int k  = lane >> 2;
    int i0 = (lane & 3) * EPT;

    float acc[EPT];
#pragma unroll
    for (int s = 0; s < EPT; ++s) acc[s] = 0.0f;

    int e0 = f_off[n], e1 = f_off[n + 1];
    for (int e = e0; e < e1; e += 4) {
        int ea = e;
        int eb = (e + 1 < e1) ? e + 1 : e;
        int ec = (e + 2 < e1) ? e + 2 : e;
        int ed = (e + 3 < e1) ? e + 3 : e;
        int s0 = fe_j[ea], s1 = fe_j[eb], s2 = fe_j[ec], s3 = fe_j[ed];
        float c0 = f_coeff[(size_t)ea * 16 + k];
        float c1 = f_coeff[(size_t)eb * 16 + k];
        float c2 = f_coeff[(size_t)ec * 16 + k];
        float c3 = f_coeff[(size_t)ed * 16 + k];
        c1 = (e + 1 < e1) ? c1 : 0.0f;
        c2 = (e + 2 < e1) ? c2 : 0.0f;
        c3 = (e + 3 < e1) ? c3 : 0.0f;
        const uint4* x0 = (const uint4*)(Xb + (size_t)s0 * CIN + i0);
        const uint4* x1 = (const uint4*)(Xb + (size_t)s1 * CIN + i0);
        const uint4* x2 = (const uint4*)(Xb + (size_t)s2 * CIN + i0);
        const uint4* x3 = (const uint4*)(Xb + (size_t)s3 * CIN + i0);
        uint4 r0[NU4], r1[NU4], r2[NU4], r3[NU4];
#pragma unroll
        for (int q = 0; q < NU4; ++q) r0[q] = x0[q];
#pragma unroll
        for (int q = 0; q < NU4; ++q) r1[q] = x1[q];
#pragma unroll
        for (int q = 0; q < NU4; ++q) r2[q] = x2[q];
#pragma unroll
        for (int q = 0; q < NU4; ++q) r3[q] = x3[q];
#pragma unroll
        for (int q = 0; q < NU4; ++q) {
            unsigned int w0[4] = {r0[q].x, r0[q].y, r0[q].z, r0[q].w};
            unsigned int w1[4] = {r1[q].x, r1[q].y, r1[q].z, r1[q].w};
            unsigned int w2[4] = {r2[q].x, r2[q].y, r2[q].z, r2[q].w};
            unsigned int w3[4] = {r3[q].x, r3[q].y, r3[q].z, r3[q].w};
#pragma unroll
            for (int j = 0; j < 4; ++j) {
                int s = q * 8 + j * 2;
#define EDGEFMA(wj, cc)                                                        \
                {                                                              \
                    float lo = bf2f((unsigned short)(wj[j] & 0xffff));         \
                    float hi = bf2f((unsigned short)(wj[j] >> 16));            \
                    if (RELU) { lo = fmaxf(lo, 0.f); hi = fmaxf(hi, 0.f); }    \
                    acc[s + 0] = fmaf(cc, lo, acc[s + 0]);                     \
                    acc[s + 1] = fmaf(cc, hi, acc[s + 1]);                     \
                }
                EDGEFMA(w0, c0)
                EDGEFMA(w1, c1)
                EDGEFMA(w2, c2)
                EDGEFMA(w3, c3)
#undef EDGEFMA
            }
        }
    }

    ushort_t* grow = Gb + (size_t)ln * KTOT;
    ushort_t* gp = grow + k * CIN + i0;
#pragma unroll
    for (int q = 0; q < NU4; ++q) {
        uint4 o;
        o.x = (unsigned int)f2bf(acc[q*8+0]) | ((unsigned int)f2bf(acc[q*8+1]) << 16);
        o.y = (unsigned int)f2bf(acc[q*8+2]) | ((unsigned int)f2bf(acc[q*8+3]) << 16);
        o.z = (unsigned int)f2bf(acc[q*8+4]) | ((unsigned int)f2bf(acc[q*8+5]) << 16);
        o.w = (unsigned int)f2bf(acc[q*8+6]) | ((unsigned int)f2bf(acc[q*8+7]) << 16);
        *(uint4*)(gp + q * 8) = o;
    }
    // appended x_hat row (bf16 copy, relu'd)
    for (int i = lane; i < CIN; i += 64) {
        ushort_t v = Xb[(size_t)n * CIN + i];
        if (RELU && (v & 0x8000)) v = 0;
        grow[16 * CIN + i] = v;
    }
}

// ---------------- gemm: K-split partial GEMM; bf16 G staged->fp32 LDS ----------------
template <int KTOT, int NSTEP>
__global__ __launch_bounds__(256) void gemm_kernel(
    const ushort_t* __restrict__ Gb,   // chunk-local rows, stride KTOT (bf16)
    const float* __restrict__ Wcat,    // [KTOT][64] k-major fp32
    float* __restrict__ P, int stride, int cnt) {
    __shared__ float Wl[68 * 64];
    __shared__ float Gl[32 * 72];
    const int t = threadIdx.x;
    const int tx = t & 31;
    const int ty = t >> 5;
    const int nb = blockIdx.x * 32;
    const int ks = blockIdx.y;
    int k0 = ks * (NSTEP * 68);

    float a00 = 0.f, a01 = 0.f, a10 = 0.f, a11 = 0.f;
    float a20 = 0.f, a21 = 0.f, a30 = 0.f, a31 = 0.f;

    for (int st = 0; st < NSTEP; ++st, k0 += 68) {
        __syncthreads();
        const float4* ws4 = (const float4*)(Wcat + (size_t)k0 * 64);
#pragma unroll
        for (int it = 0; it < 5; ++it) {
            int idx = it * 256 + t;
            if (idx < 1088) ((float4*)Wl)[idx] = ws4[idx];
        }
#pragma unroll
        for (int it = 0; it < 3; ++it) {
            int idx = it * 256 + t;
            if (idx < 544) {
                int n = idx / 17, off = idx - n * 17;
                int gn = nb + n;
                if (gn > cnt - 1) gn = cnt - 1;
                uint2 raw = *(const uint2*)(Gb + (size_t)gn * KTOT + k0 + off * 4);
                float4 v;
                v.x = bf2f((unsigned short)(raw.x & 0xffff));
                v.y = bf2f((unsigned short)(raw.x >> 16));
                v.z = bf2f((unsigned short)(raw.y & 0xffff));
                v.w = bf2f((unsigned short)(raw.y >> 16));
                *(float4*)(Gl + n * 72 + off * 4) = v;
            }
        }
        __syncthreads();

        const float* g0p = Gl + (4 * ty + 0) * 72;
        const float* g1p = Gl + (4 * ty + 1) * 72;
        const float* g2p = Gl + (4 * ty + 2) * 72;
        const float* g3p = Gl + (4 * ty + 3) * 72;
        const float* wp  = Wl + tx * 2;
#pragma unroll 2
        for (int kk = 0; kk < 68; kk += 4) {
            float4 g0 = *(const float4*)(g0p + kk);
            float4 g1 = *(const float4*)(g1p + kk);
            float4 g2 = *(const float4*)(g2p + kk);
            float4 g3 = *(const float4*)(g3p + kk);
#define GSTEP(u, comp)                                            \
            {                                                     \
                float2 w = *(const float2*)(wp + (kk + u) * 64);  \
                a00 = fmaf(g0.comp, w.x, a00);                    \
                a01 = fmaf(g0.comp, w.y, a01);                    \
                a10 = fmaf(g1.comp, w.x, a10);                    \
                a11 = fmaf(g1.comp, w.y, a11);                    \
                a20 = fmaf(g2.comp, w.x, a20);                    \
                a21 = fmaf(g2.comp, w.y, a21);                    \
                a30 = fmaf(g3.comp, w.x, a30);                    \
                a31 = fmaf(g3.comp, w.y, a31);                    \
            }
            GSTEP(0, x) GSTEP(1, y) GSTEP(2, z) GSTEP(3, w)
#undef GSTEP
        }
    }

    float* pb = P + ((size_t)ks * stride + nb) * 64 + tx * 2;
    int rem = cnt - nb;
    if (4 * ty + 0 < rem) *(float2*)(pb + (4 * ty + 0) * 64) = make_float2(a00, a01);
    if (4 * ty + 1 < rem) *(float2*)(pb + (4 * ty + 1) * 64) = make_float2(a10, a11);
    if (4 * ty + 2 < rem) *(float2*)(pb + (4 * ty + 2) * 64) = make_float2(a20, a21);
    if (4 * ty + 3 < rem) *(float2*)(pb + (4 * ty + 3) * 64) = make_float2(a30, a31);
}

// ---------------- reduce: sum partials + bias (+bf16 resid) -> bf16 or fp32 ----------------
template <bool RESID, bool FINAL, bool OUTBF>
__global__ void reduce_kernel(const float* __restrict__ P, int stride,
                              const float* __restrict__ bA, const float* __restrict__ bB,
                              const float* __restrict__ fcb,
                              const ushort_t* __restrict__ XresB,
                              void* __restrict__ OUT, int nodeBase, int cnt) {
    int idx = blockIdx.x * 256 + threadIdx.x;
    if (idx >= cnt * 64) return;
    int ln = idx >> 6, o = idx & 63;
    float s = ((o < 32) ? bA[o] : bB[o - 32]) + fcb[o];
#pragma unroll
    for (int ks = 0; ks < KS; ++ks) s += P[((size_t)ks * stride + ln) * 64 + o];
    int node = nodeBase + ln;
    if (RESID) s += bf2f(XresB[(size_t)node * 64 + o]);
    if (FINAL) s *= (1.0f / 128.0f);
    if (OUTBF) ((ushort_t*)OUT)[(size_t)node * 64 + o] = f2bf(s);
    else       ((float*)OUT)[(size_t)node * 64 + o] = s;
}

// ---------------- fallback path (bf16 X variant of proven round-2 kernel) ----------------
template <int CIN, bool RELU_IN, bool RESIDUAL, bool FINAL, bool OUTBF>
__global__ __launch_bounds__(256) void conv_layer_kernel(
    const ushort_t* __restrict__ Xb,
    const float* __restrict__ WA, const float* __restrict__ bA,
    const float* __restrict__ WB, const float* __restrict__ bB,
    const float* __restrict__ fcW, const float* __restrict__ fcb,
    const int* __restrict__ f_off, const int* __restrict__ fe_j,
    const float* __restrict__ f_coeff,
    void* __restrict__ OUT) {
    constexpr int NELEM = 16 * CIN;
    constexpr int EPT = NELEM / 256;
    constexpr int BATCH = 8;
    constexpr int CHUNK = NELEM / 4;

    __shared__ float x_lds[CIN];
    __shared__ float feat[BATCH][CIN];
    __shared__ float co[BATCH][16];
    __shared__ float Gs[NELEM];
    __shared__ float red[4][64];

    int n = blockIdx.x;
    int t = threadIdx.x;

    for (int i = t; i < CIN; i += 256) {
        float v = bf2f(Xb[(size_t)n * CIN + i]);
        if (RELU_IN) v = fmaxf(v, 0.0f);
        x_lds[i] = v;
    }

    float acc[EPT];
    int kk[EPT], ii[EPT];
#pragma unroll
    for (int s = 0; s < EPT; ++s) {
        acc[s] = 0.0f;
        int j = s * 256 + t;
        kk[s] = j / CIN;
        ii[s] = j - kk[s] * CIN;
    }

    int e0 = f_off[n], e1 = f_off[n + 1];
    for (int eb = e0; eb < e1; eb += BATCH) {
        int cnt = min(BATCH, e1 - eb);
        __syncthreads();
        for (int idx = t; idx < cnt * 16; idx += 256) {
            int b = idx >> 4, c = idx & 15;
            co[b][c] = f_coeff[(size_t)(eb + b) * 16 + c];
        }
        for (int idx = t; idx < cnt * CIN; idx += 256) {
            int b = idx / CIN, i = idx - b * CIN;
            int srcn = fe_j[eb + b];
            float v = bf2f(Xb[(size_t)srcn * CIN + i]);
            if (RELU_IN) v = fmaxf(v, 0.0f);
            feat[b][i] = v;
        }
        __syncthreads();
#pragma unroll
        for (int b = 0; b < BATCH; ++b) {
            if (b >= cnt) break;
#pragma unroll
            for (int s = 0; s < EPT; ++s) acc[s] += co[b][kk[s]] * feat[b][ii[s]];
        }
    }
    __syncthreads();
#pragma unroll
    for (int s = 0; s < EPT; ++s) Gs[s * 256 + t] = acc[s];
    __syncthreads();

    int o = t & 63;
    int chunk = t >> 6;
    const float* Wp = (o < 32) ? WA : WB;
    int oc = o & 31;
    int j0 = chunk * CHUNK;
    float p0 = 0.f, p1 = 0.f, p2 = 0.f, p3 = 0.f;
    for (int j = j0; j < j0 + CHUNK; j += 4) {
        p0 += Gs[j + 0] * Wp[(size_t)(j + 0) * 32 + oc];
        p1 += Gs[j + 1] * Wp[(size_t)(j + 1) * 32 + oc];
        p2 += Gs[j + 2] * Wp[(size_t)(j + 2) * 32 + oc];
        p3 += Gs[j + 3] * Wp[(size_t)(j + 3) * 32 + oc];
    }
    red[chunk][o] = ((p0 + p1) + (p2 + p3));
    __syncthreads();
    if (t < 64) {
        float s = red[0][o] + red[1][o] + red[2][o] + red[3][o];
        s += (o < 32) ? bA[oc] : bB[oc];
        float fcv = fcb[o];
        for (int i = 0; i < CIN; ++i) fcv += x_lds[i] * fcW[i * 64 + o];
        s += fcv;
        if (RESIDUAL) s += bf2f(Xb[(size_t)n * 64 + o]);
        if (FINAL) s *= (1.0f / 128.0f);
        if (OUTBF) ((ushort_t*)OUT)[(size_t)n * 64 + o] = f2bf(s);
        else       ((float*)OUT)[(size_t)n * 64 + o] = s;
    }
}

extern "C" void kernel_launch(void* const* d_in, const int* in_sizes, int n_in,
                              void* d_out, int out_size, void* d_ws, size_t ws_size,
                              hipStream_t stream) {
    const float* fluidPos      = (const float*)d_in[0];
    const float* boundaryPos   = (const float*)d_in[1];
    const float* fluidFeats    = (const float*)d_in[2];
    const float* boundaryFeats = (const float*)d_in[3];
    const int* fe_i = (const int*)d_in[4];
    const int* fe_j = (const int*)d_in[5];
    const int* be_f = (const int*)d_in[6];
    const int* be_b = (const int*)d_in[7];
    const float* W[8];
    const float* bb[8];
    for (int c = 0; c < 8; ++c) {
        W[c]  = (const float*)d_in[8 + 2 * c];
        bb[c] = (const float*)d_in[9 + 2 * c];
    }
    const float* fcW0 = (const float*)d_in[24];
    const float* fcb0 = (const float*)d_in[25];
    const float* fcW1 = (const float*)d_in[26];
    const float* fcb1 = (const float*)d_in[27];
    const float* fcW2 = (const float*)d_in[28];
    const float* fcb2 = (const float*)d_in[29];

    int NF = in_sizes[0] / 2;
    int EF = in_sizes[4];
    int EB = in_sizes[6];

    // ---- workspace layout (f32 units; all segments multiples of 4 -> 16B aligned) ----
    float* ws = (float*)d_ws;
    size_t p = 0;
    float* f_coeff = ws + p;  p += (size_t)EF * 16;
    float* b_coeff = ws + p;  p += (size_t)EB * 16;
    ushort_t* A1b  = (ushort_t*)(ws + p);  p += (size_t)NF * 48;   // NF*96 bf16
    ushort_t* ans2b= (ushort_t*)(ws + p);  p += (size_t)NF * 32;   // NF*64 bf16
    int*   f_off   = (int*)(ws + p);  p += (size_t)((NF + 4) & ~3);
    int*   b_off   = (int*)(ws + p);  p += (size_t)((NF + 4) & ~3);
    float* Wc2     = ws + p;  p += 1632 * 64;   // [KTOT][64] k-major fp32
    float* Wc3     = ws + p;  p += 1088 * 64;
    float* Gregion = ws + p;
    size_t gBase = p;

    long wsFloats = (long)(ws_size / 4);
    long avail = wsFloats - (long)gBase;
    int chunk2 = 0, chunk3 = 0;
    if (avail > 0) {
        long per2 = 1632 / 2 + KS * 64, per3 = 1088 / 2 + KS * 64;  // bf16 G + fp32 P
        chunk2 = (int)((avail / per2 < (long)NF) ? avail / per2 : NF) & ~31;
        chunk3 = (int)((avail / per3 < (long)NF) ? avail / per3 : NF) & ~31;
    }
    bool bigPath = (chunk2 >= 32) && (chunk3 >= 32);

    // ---- shared prologue ----
    coeff_kernel<true><<<(EF + 255) / 256, 256, 0, stream>>>(
        (const float2*)fluidPos, fe_j, (const float2*)fluidPos, fe_i, f_coeff, EF);
    coeff_kernel<false><<<(EB + 255) / 256, 256, 0, stream>>>(
        (const float2*)boundaryPos, be_b, (const float2*)fluidPos, be_f, b_coeff, EB);
    offsets_kernel<<<(NF + 1 + 255) / 256, 256, 0, stream>>>(fe_i, EF, f_off, NF + 1);
    offsets_kernel<<<(NF + 1 + 255) / 256, 256, 0, stream>>>(be_f, EB, b_off, NF + 1);

    layer1_kernel<<<NF, 128, 0, stream>>>(fluidFeats, boundaryFeats, fcW0, fcb0,
                                          W[0], bb[0], W[1], bb[1], W[2], bb[2], W[3], bb[3],
                                          f_off, fe_j, f_coeff, b_off, be_b, b_coeff, A1b);

    if (bigPath) {
        prep_kernel<<<(1632 * 64 + 255) / 256, 256, 0, stream>>>(W[4], W[5], fcW1, Wc2, 96, 1632);
        prep_kernel<<<(1088 * 64 + 255) / 256, 256, 0, stream>>>(W[6], W[7], fcW2, Wc3, 64, 1088);

        // layer 2: A1b (relu'd bf16) -> ans2b (bf16)
        {
            ushort_t* Gb = (ushort_t*)Gregion;
            float* Pbuf = Gregion + (size_t)chunk2 * (1632 / 2);
            for (int s = 0; s < NF; s += chunk2) {
                int cnt = (NF - s < chunk2) ? (NF - s) : chunk2;
                int nblocks = (cnt + 31) / 32;
                buildG_kernel<96, false><<<(cnt + 3) / 4, 256, 0, stream>>>(
                    A1b, f_off, fe_j, f_coeff, Gb, s, cnt);
                gemm_kernel<1632, 3><<<dim3(nblocks, KS), 256, 0, stream>>>(
                    Gb, Wc2, Pbuf, chunk2, cnt);
                reduce_kernel<false, false, true><<<(cnt * 64 + 255) / 256, 256, 0, stream>>>(
                    Pbuf, chunk2, bb[4], bb[5], fcb1, nullptr, ans2b, s, cnt);
            }
        }
        // layer 3: relu(ans2b) -> d_out (fp32), +bf16 residual, /128
        {
            ushort_t* Gb = (ushort_t*)Gregion;
            float* Pbuf = Gregion + (size_t)chunk3 * (1088 / 2);
            for (int s = 0; s < NF; s += chunk3) {
                int cnt = (NF - s < chunk3) ? (NF - s) : chunk3;
                int nblocks = (cnt + 31) / 32;
                buildG_kernel<64, true><<<(cnt + 3) / 4, 256, 0, stream>>>(
                    ans2b, f_off, fe_j, f_coeff, Gb, s, cnt);
                gemm_kernel<1088, 2><<<dim3(nblocks, KS), 256, 0, stream>>>(
                    Gb, Wc3, Pbuf, chunk3, cnt);
                reduce_kernel<true, true, false><<<(cnt * 64 + 255) / 256, 256, 0, stream>>>(
                    Pbuf, chunk3, bb[6], bb[7], fcb2, ans2b, d_out, s, cnt);
            }
        }
    } else {
        conv_layer_kernel<96, false, false, false, true><<<NF, 256, 0, stream>>>(
            A1b, W[4], bb[4], W[5], bb[5], fcW1, fcb1, f_off, fe_j, f_coeff, ans2b);
        conv_layer_kernel<64, true, true, true, false><<<NF, 256, 0, stream>>>(
            ans2b, W[6], bb[6], W[7], bb[7], fcW2, fcb2, f_off, fe_j, f_coeff, d_out);
    }
}

// Round 12
// 123.057 us; speedup vs baseline: 2.2344x; 1.4714x over previous
//
#include <hip/hip_runtime.h>
#include <math.h>

#define SUPPORT 1.5f

typedef unsigned short ushort_t;
typedef short bf16x8 __attribute__((ext_vector_type(8)));
typedef float f32x4 __attribute__((ext_vector_type(4)));

__device__ __forceinline__ float bf2f(unsigned short h) {
    union { unsigned int u; float f; } c;
    c.u = ((unsigned int)h) << 16;
    return c.f;
}
__device__ __forceinline__ unsigned short f2bf(float f) {
    union { float f; unsigned int u; } c;
    c.f = f;
    unsigned int lsb = (c.u >> 16) & 1u;
    c.u += 0x7fffu + lsb;   // round-to-nearest-even
    return (unsigned short)(c.u >> 16);
}

// ---------------- hat basis ----------------
__device__ __forceinline__ void hat4(float u, float h[4]) {
#pragma unroll
    for (int j = 0; j < 4; ++j) {
        float c = -1.0f + j * (2.0f / 3.0f);
        h[j] = fmaxf(0.0f, 1.0f - fabsf(u - c) * 1.5f);
    }
}

// ---------------- per-edge RBF coefficients ----------------
template <bool NEG>
__global__ void coeff_kernel(const float2* __restrict__ pa, const int* __restrict__ ia,
                             const float2* __restrict__ pb, const int* __restrict__ ib,
                             float* __restrict__ out, int E) {
    int e = blockIdx.x * blockDim.x + threadIdx.x;
    if (e >= E) return;
    float2 A = pa[ia[e]];
    float2 B = pb[ib[e]];
    float rx = (A.x - B.x) / SUPPORT;
    float ry = (A.y - B.y) / SUPPORT;
    if (NEG) { rx = -rx; ry = -ry; }
    float dx = fminf(fmaxf(rx, -1.0f), 1.0f);
    float dy = fminf(fmaxf(ry, -1.0f), 1.0f);
    float r  = sqrtf(dx * dx + dy * dy) * 2.0f - 1.0f;
    float th = atan2f(dy, dx) / 3.14159265358979323846f;
    float hr[4], ht[4];
    hat4(r, hr);
    hat4(th, ht);
    float* o = out + (size_t)e * 16;
#pragma unroll
    for (int a = 0; a < 4; ++a)
#pragma unroll
        for (int b = 0; b < 4; ++b)
            o[a * 4 + b] = hr[a] * ht[b];
}

// ---------------- CSR offsets ----------------
__global__ void offsets_kernel(const int* __restrict__ sorted, int E,
                               int* __restrict__ off, int N1) {
    int i = blockIdx.x * blockDim.x + threadIdx.x;
    if (i >= N1) return;
    int lo = 0, hi = E;
    while (lo < hi) {
        int mid = (lo + hi) >> 1;
        if (sorted[mid] < i) lo = mid + 1; else hi = mid;
    }
    off[i] = lo;
}

// ---------------- layer 1 (small Cin, direct); W columns hoisted ----------------
__global__ void layer1_kernel(const float* __restrict__ fluidFeats,
                              const float* __restrict__ boundaryFeats,
                              const float* __restrict__ fcW0, const float* __restrict__ fcb0,
                              const float* __restrict__ W0, const float* __restrict__ b0,
                              const float* __restrict__ W1, const float* __restrict__ b1,
                              const float* __restrict__ W2, const float* __restrict__ b2,
                              const float* __restrict__ W3, const float* __restrict__ b3,
                              const int* __restrict__ f_off, const int* __restrict__ fe_j,
                              const float* __restrict__ f_coeff,
                              const int* __restrict__ b_off, const int* __restrict__ be_b,
                              const float* __restrict__ b_coeff,
                              ushort_t* __restrict__ A1b) {
    int n = blockIdx.x;
    int t = threadIdx.x;
    if (t >= 96) return;
    float val;
    if (t < 32) {
        val = fluidFeats[n * 2] * fcW0[t] + fluidFeats[n * 2 + 1] * fcW0[32 + t] + fcb0[t];
    } else if (t < 64) {
        int oc = t - 32;
        const float* W = (oc < 16) ? W0 : W1;
        int o16 = oc & 15;
        float wk[32];
#pragma unroll
        for (int k = 0; k < 16; ++k) {
            wk[2 * k + 0] = W[(k * 2 + 0) * 16 + o16];
            wk[2 * k + 1] = W[(k * 2 + 1) * 16 + o16];
        }
        float s = (oc < 16) ? b0[o16] : b1[o16];
        int e1 = f_off[n + 1];
        for (int e = f_off[n]; e < e1; ++e) {
            const float* cf = f_coeff + (size_t)e * 16;
            int srcn = fe_j[e];
            float f0 = fluidFeats[srcn * 2], f1 = fluidFeats[srcn * 2 + 1];
            float acc = 0.0f;
#pragma unroll
            for (int k = 0; k < 16; ++k)
                acc += cf[k] * (f0 * wk[2 * k] + f1 * wk[2 * k + 1]);
            s += acc;
        }
        val = s;
    } else {
        int oc = t - 64;
        const float* W = (oc < 16) ? W2 : W3;
        int o16 = oc & 15;
        float wk[48];
#pragma unroll
        for (int k = 0; k < 16; ++k) {
            wk[3 * k + 0] = W[(k * 3 + 0) * 16 + o16];
            wk[3 * k + 1] = W[(k * 3 + 1) * 16 + o16];
            wk[3 * k + 2] = W[(k * 3 + 2) * 16 + o16];
        }
        float s = (oc < 16) ? b2[o16] : b3[o16];
        int e1 = b_off[n + 1];
        for (int e = b_off[n]; e < e1; ++e) {
            const float* cf = b_coeff + (size_t)e * 16;
            int srcn = be_b[e];
            float f0 = boundaryFeats[srcn * 3], f1 = boundaryFeats[srcn * 3 + 1],
                  f2 = boundaryFeats[srcn * 3 + 2];
            float acc = 0.0f;
#pragma unroll
            for (int k = 0; k < 16; ++k)
                acc += cf[k] * (f0 * wk[3 * k] + f1 * wk[3 * k + 1] + f2 * wk[3 * k + 2]);
            s += acc;
        }
        val = s;
    }
    A1b[(size_t)n * 96 + t] = f2bf(fmaxf(val, 0.0f));
}

// ---------------- prep: pack W into MFMA B-fragment layout (bf16) + fused bias ----------------
// Wp[((ks*4 + tile)*64 + lane)*8 + j] = bf16( Wsrc[k = ks*32 + (lane>>4)*8 + j][o = tile*16 + (lane&15)] )
// Wsrc row j<16CIN: o<32 -> WA[j*32+o] else WB[j*32+o-32]; j>=16CIN -> fcW[(j-16CIN)*64+o]
__global__ void prep_mfma_kernel(const float* __restrict__ WA, const float* __restrict__ WB,
                                 const float* __restrict__ fcW,
                                 const float* __restrict__ bA, const float* __restrict__ bB,
                                 const float* __restrict__ fcb,
                                 ushort_t* __restrict__ Wp, float* __restrict__ bias,
                                 int CIN, int KSTEPS) {
    int idx = blockIdx.x * 256 + threadIdx.x;
    if (idx < 64) bias[idx] = ((idx < 32) ? bA[idx] : bB[idx - 32]) + fcb[idx];
    int total = KSTEPS * 2048;   // KSTEPS*4*64*8 = KTOT*64
    if (idx >= total) return;
    int j8   = idx & 7;
    int lane = (idx >> 3) & 63;
    int tile = (idx >> 9) & 3;
    int ks   = idx >> 11;
    int kk = ks * 32 + ((lane >> 4) << 3) + j8;
    int o  = tile * 16 + (lane & 15);
    int KC = 16 * CIN;
    float v = (kk < KC) ? ((o < 32) ? WA[(size_t)kk * 32 + o] : WB[(size_t)kk * 32 + (o - 32)])
                        : fcW[(size_t)(kk - KC) * 64 + o];
    Wp[idx] = f2bf(v);
}

// ---------------- fused conv: buildG(LDS) + MFMA + epilogue ----------------
// Block: 16 nodes, 256 thr = 4 waves. Wave wv builds nodes 4wv..4wv+3, then computes
// out-tile [16wv, 16wv+16) via mfma_f32_16x16x32_bf16 over KTOT.
template <int CIN, bool RELU, bool RESID, bool FINAL>
__global__ __launch_bounds__(256) void conv_mfma_kernel(
    const ushort_t* __restrict__ Xb,
    const int* __restrict__ f_off, const int* __restrict__ fe_j,
    const float* __restrict__ f_coeff,
    const ushort_t* __restrict__ Wp, const float* __restrict__ bias,
    const ushort_t* __restrict__ XresB,
    void* __restrict__ OUT, int NF) {
    constexpr int KTOT   = 17 * CIN;        // 1632 or 1088
    constexpr int KSTEPS = KTOT / 32;       // 51 or 34
    constexpr int STRIDE = KTOT + 8;        // pad: stride%32 words -> 2-way-free b128 reads
    constexpr int EPT = CIN / 4;            // 24 or 16 bf16 per lane
    constexpr int NU4 = EPT / 8;            // 3 or 2 uint4 per edge-lane

    __shared__ ushort_t Gl[16 * STRIDE];

    const int t = threadIdx.x;
    const int wv = t >> 6;
    const int lane = t & 63;
    const int nb = blockIdx.x * 16;

    // ---- phase 1: build G rows (wave-per-node, 4 nodes per wave) ----
    const int k  = lane >> 2;
    const int i0 = (lane & 3) * EPT;
    for (int s4 = 0; s4 < 4; ++s4) {
        int lnode = wv * 4 + s4;
        int n = nb + lnode;
        if (n > NF - 1) n = NF - 1;

        float acc[EPT];
#pragma unroll
        for (int s = 0; s < EPT; ++s) acc[s] = 0.0f;

        int e0 = f_off[n], e1 = f_off[n + 1];
        for (int e = e0; e < e1; e += 4) {
            int ea = e;
            int eb = (e + 1 < e1) ? e + 1 : e;
            int ec = (e + 2 < e1) ? e + 2 : e;
            int ed = (e + 3 < e1) ? e + 3 : e;
            int s0 = fe_j[ea], s1 = fe_j[eb], s2 = fe_j[ec], s3 = fe_j[ed];
            float c0 = f_coeff[(size_t)ea * 16 + k];
            float c1 = f_coeff[(size_t)eb * 16 + k];
            float c2 = f_coeff[(size_t)ec * 16 + k];
            float c3 = f_coeff[(size_t)ed * 16 + k];
            c1 = (e + 1 < e1) ? c1 : 0.0f;
            c2 = (e + 2 < e1) ? c2 : 0.0f;
            c3 = (e + 3 < e1) ? c3 : 0.0f;
            const uint4* x0 = (const uint4*)(Xb + (size_t)s0 * CIN + i0);
            const uint4* x1 = (const uint4*)(Xb + (size_t)s1 * CIN + i0);
            const uint4* x2 = (const uint4*)(Xb + (size_t)s2 * CIN + i0);
            const uint4* x3 = (const uint4*)(Xb + (size_t)s3 * CIN + i0);
            uint4 r0[NU4], r1[NU4], r2[NU4], r3[NU4];
#pragma unroll
            for (int q = 0; q < NU4; ++q) r0[q] = x0[q];
#pragma unroll
            for (int q = 0; q < NU4; ++q) r1[q] = x1[q];
#pragma unroll
            for (int q = 0; q < NU4; ++q) r2[q] = x2[q];
#pragma unroll
            for (int q = 0; q < NU4; ++q) r3[q] = x3[q];
#pragma unroll
            for (int q = 0; q < NU4; ++q) {
                unsigned int w0[4] = {r0[q].x, r0[q].y, r0[q].z, r0[q].w};
                unsigned int w1[4] = {r1[q].x, r1[q].y, r1[q].z, r1[q].w};
                unsigned int w2[4] = {r2[q].x, r2[q].y, r2[q].z, r2[q].w};
                unsigned int w3[4] = {r3[q].x, r3[q].y, r3[q].z, r3[q].w};
#pragma unroll
                for (int j = 0; j < 4; ++j) {
                    int s = q * 8 + j * 2;
#define EDGEFMA(wj, cc)                                                        \
                    {                                                          \
                        float lo = bf2f((unsigned short)(wj[j] & 0xffff));     \
                        float hi = bf2f((unsigned short)(wj[j] >> 16));        \
                        if (RELU) { lo = fmaxf(lo, 0.f); hi = fmaxf(hi, 0.f); }\
                        acc[s + 0] = fmaf(cc, lo, acc[s + 0]);                 \
                        acc[s + 1] = fmaf(cc, hi, acc[s + 1]);                 \
                    }
                    EDGEFMA(w0, c0)
                    EDGEFMA(w1, c1)
                    EDGEFMA(w2, c2)
                    EDGEFMA(w3, c3)
#undef EDGEFMA
                }
            }
        }

        ushort_t* grow = Gl + lnode * STRIDE;
        ushort_t* gp = grow + k * CIN + i0;
#pragma unroll
        for (int q = 0; q < NU4; ++q) {
            uint4 o;
            o.x = (unsigned int)f2bf(acc[q*8+0]) | ((unsigned int)f2bf(acc[q*8+1]) << 16);
            o.y = (unsigned int)f2bf(acc[q*8+2]) | ((unsigned int)f2bf(acc[q*8+3]) << 16);
            o.z = (unsigned int)f2bf(acc[q*8+4]) | ((unsigned int)f2bf(acc[q*8+5]) << 16);
            o.w = (unsigned int)f2bf(acc[q*8+6]) | ((unsigned int)f2bf(acc[q*8+7]) << 16);
            *(uint4*)(gp + q * 8) = o;
        }
        // x_hat row (bf16, relu'd)
        for (int i = lane; i < CIN; i += 64) {
            ushort_t v = Xb[(size_t)n * CIN + i];
            if (RELU && (v & 0x8000)) v = 0;
            grow[16 * CIN + i] = v;
        }
    }
    __syncthreads();

    // ---- phase 2: MFMA [16 nodes x KTOT] @ [KTOT x 16 outs] ----
    f32x4 cacc = {0.f, 0.f, 0.f, 0.f};
    const int arow = lane & 15;
    const int koff = (lane >> 4) << 3;
    const ushort_t* garow = Gl + arow * STRIDE + koff;
    const ushort_t* wpp = Wp + ((size_t)(wv * 64 + lane) << 3);
    for (int ks = 0; ks < KSTEPS; ++ks) {
        bf16x8 a = *(const bf16x8*)(garow + ks * 32);
        bf16x8 b = *(const bf16x8*)(wpp + (size_t)ks * 2048);   // (ks*4)*64*8
        cacc = __builtin_amdgcn_mfma_f32_16x16x32_bf16(a, b, cacc, 0, 0, 0);
    }

    // ---- epilogue: D[node=(lane>>4)*4+r][o=lane&15] ----
    int o = wv * 16 + (lane & 15);
    float bo = bias[o];
#pragma unroll
    for (int r = 0; r < 4; ++r) {
        int node = nb + ((lane >> 4) << 2) + r;
        if (node < NF) {
            float s = cacc[r] + bo;
            if (RESID) s += bf2f(XresB[(size_t)node * 64 + o]);
            if (FINAL) {
                ((float*)OUT)[(size_t)node * 64 + o] = s * (1.0f / 128.0f);
            } else {
                ((ushort_t*)OUT)[(size_t)node * 64 + o] = f2bf(s);
            }
        }
    }
}

// ---------------- fallback path (bf16 X, fp32 W; proven) ----------------
template <int CIN, bool RELU_IN, bool RESIDUAL, bool FINAL, bool OUTBF>
__global__ __launch_bounds__(256) void conv_layer_kernel(
    const ushort_t* __restrict__ Xb,
    const float* __restrict__ WA, const float* __restrict__ bA,
    const float* __restrict__ WB, const float* __restrict__ bB,
    const float* __restrict__ fcW, const float* __restrict__ fcb,
    const int* __restrict__ f_off, const int* __restrict__ fe_j,
    const float* __restrict__ f_coeff,
    void* __restrict__ OUT) {
    constexpr int NELEM = 16 * CIN;
    constexpr int EPT = NELEM / 256;
    constexpr int BATCH = 8;
    constexpr int CHUNK = NELEM / 4;

    __shared__ float x_lds[CIN];
    __shared__ float feat[BATCH][CIN];
    __shared__ float co[BATCH][16];
    __shared__ float Gs[NELEM];
    __shared__ float red[4][64];

    int n = blockIdx.x;
    int t = threadIdx.x;

    for (int i = t; i < CIN; i += 256) {
        float v = bf2f(Xb[(size_t)n * CIN + i]);
        if (RELU_IN) v = fmaxf(v, 0.0f);
        x_lds[i] = v;
    }

    float acc[EPT];
    int kk[EPT], ii[EPT];
#pragma unroll
    for (int s = 0; s < EPT; ++s) {
        acc[s] = 0.0f;
        int j = s * 256 + t;
        kk[s] = j / CIN;
        ii[s] = j - kk[s] * CIN;
    }

    int e0 = f_off[n], e1 = f_off[n + 1];
    for (int eb = e0; eb < e1; eb += BATCH) {
        int cnt = min(BATCH, e1 - eb);
        __syncthreads();
        for (int idx = t; idx < cnt * 16; idx += 256) {
            int b = idx >> 4, c = idx & 15;
            co[b][c] = f_coeff[(size_t)(eb + b) * 16 + c];
        }
        for (int idx = t; idx < cnt * CIN; idx += 256) {
            int b = idx / CIN, i = idx - b * CIN;
            int srcn = fe_j[eb + b];
            float v = bf2f(Xb[(size_t)srcn * CIN + i]);
            if (RELU_IN) v = fmaxf(v, 0.0f);
            feat[b][i] = v;
        }
        __syncthreads();
#pragma unroll
        for (int b = 0; b < BATCH; ++b) {
            if (b >= cnt) break;
#pragma unroll
            for (int s = 0; s < EPT; ++s) acc[s] += co[b][kk[s]] * feat[b][ii[s]];
        }
    }
    __syncthreads();
#pragma unroll
    for (int s = 0; s < EPT; ++s) Gs[s * 256 + t] = acc[s];
    __syncthreads();

    int o = t & 63;
    int chunk = t >> 6;
    const float* Wp = (o < 32) ? WA : WB;
    int oc = o & 31;
    int j0 = chunk * CHUNK;
    float p0 = 0.f, p1 = 0.f, p2 = 0.f, p3 = 0.f;
    for (int j = j0; j < j0 + CHUNK; j += 4) {
        p0 += Gs[j + 0] * Wp[(size_t)(j + 0) * 32 + oc];
        p1 += Gs[j + 1] * Wp[(size_t)(j + 1) * 32 + oc];
        p2 += Gs[j + 2] * Wp[(size_t)(j + 2) * 32 + oc];
        p3 += Gs[j + 3] * Wp[(size_t)(j + 3) * 32 + oc];
    }
    red[chunk][o] = ((p0 + p1) + (p2 + p3));
    __syncthreads();
    if (t < 64) {
        float s = red[0][o] + red[1][o] + red[2][o] + red[3][o];
        s += (o < 32) ? bA[oc] : bB[oc];
        float fcv = fcb[o];
        for (int i = 0; i < CIN; ++i) fcv += x_lds[i] * fcW[i * 64 + o];
        s += fcv;
        if (RESIDUAL) s += bf2f(Xb[(size_t)n * 64 + o]);
        if (FINAL) s *= (1.0f / 128.0f);
        if (OUTBF) ((ushort_t*)OUT)[(size_t)n * 64 + o] = f2bf(s);
        else       ((float*)OUT)[(size_t)n * 64 + o] = s;
    }
}

extern "C" void kernel_launch(void* const* d_in, const int* in_sizes, int n_in,
                              void* d_out, int out_size, void* d_ws, size_t ws_size,
                              hipStream_t stream) {
    const float* fluidPos      = (const float*)d_in[0];
    const float* boundaryPos   = (const float*)d_in[1];
    const float* fluidFeats    = (const float*)d_in[2];
    const float* boundaryFeats = (const float*)d_in[3];
    const int* fe_i = (const int*)d_in[4];
    const int* fe_j = (const int*)d_in[5];
    const int* be_f = (const int*)d_in[6];
    const int* be_b = (const int*)d_in[7];
    const float* W[8];
    const float* bb[8];
    for (int c = 0; c < 8; ++c) {
        W[c]  = (const float*)d_in[8 + 2 * c];
        bb[c] = (const float*)d_in[9 + 2 * c];
    }
    const float* fcW0 = (const float*)d_in[24];
    const float* fcb0 = (const float*)d_in[25];
    const float* fcW1 = (const float*)d_in[26];
    const float* fcb1 = (const float*)d_in[27];
    const float* fcW2 = (const float*)d_in[28];
    const float* fcb2 = (const float*)d_in[29];

    int NF = in_sizes[0] / 2;
    int EF = in_sizes[4];
    int EB = in_sizes[6];

    // ---- workspace layout (f32 units; all segments multiples of 4 -> 16B aligned) ----
    float* ws = (float*)d_ws;
    size_t p = 0;
    float* f_coeff = ws + p;  p += (size_t)EF * 16;
    float* b_coeff = ws + p;  p += (size_t)EB * 16;
    ushort_t* A1b  = (ushort_t*)(ws + p);  p += (size_t)NF * 48;   // NF*96 bf16
    ushort_t* ans2b= (ushort_t*)(ws + p);  p += (size_t)NF * 32;   // NF*64 bf16
    int*   f_off   = (int*)(ws + p);  p += (size_t)((NF + 4) & ~3);
    int*   b_off   = (int*)(ws + p);  p += (size_t)((NF + 4) & ~3);
    ushort_t* Wp2  = (ushort_t*)(ws + p);  p += 1632 * 32;   // 1632*64 bf16
    float* bias2   = ws + p;  p += 64;
    ushort_t* Wp3  = (ushort_t*)(ws + p);  p += 1088 * 32;   // 1088*64 bf16
    float* bias3   = ws + p;  p += 64;

    bool bigPath = (ws_size / 4 >= p);

    // ---- shared prologue ----
    coeff_kernel<true><<<(EF + 255) / 256, 256, 0, stream>>>(
        (const float2*)fluidPos, fe_j, (const float2*)fluidPos, fe_i, f_coeff, EF);
    coeff_kernel<false><<<(EB + 255) / 256, 256, 0, stream>>>(
        (const float2*)boundaryPos, be_b, (const float2*)fluidPos, be_f, b_coeff, EB);
    offsets_kernel<<<(NF + 1 + 255) / 256, 256, 0, stream>>>(fe_i, EF, f_off, NF + 1);
    offsets_kernel<<<(NF + 1 + 255) / 256, 256, 0, stream>>>(be_f, EB, b_off, NF + 1);

    layer1_kernel<<<NF, 128, 0, stream>>>(fluidFeats, boundaryFeats, fcW0, fcb0,
                                          W[0], bb[0], W[1], bb[1], W[2], bb[2], W[3], bb[3],
                                          f_off, fe_j, f_coeff, b_off, be_b, b_coeff, A1b);

    if (bigPath) {
        prep_mfma_kernel<<<(51 * 2048 + 255) / 256, 256, 0, stream>>>(
            W[4], W[5], fcW1, bb[4], bb[5], fcb1, Wp2, bias2, 96, 51);
        prep_mfma_kernel<<<(34 * 2048 + 255) / 256, 256, 0, stream>>>(
            W[6], W[7], fcW2, bb[6], bb[7], fcb2, Wp3, bias3, 64, 34);

        int nblk = (NF + 15) / 16;
        // layer 2: A1b (relu'd bf16) -> ans2b (bf16)
        conv_mfma_kernel<96, false, false, false><<<nblk, 256, 0, stream>>>(
            A1b, f_off, fe_j, f_coeff, Wp2, bias2, nullptr, ans2b, NF);
        // layer 3: relu(ans2b) -> d_out (fp32), + bf16 residual, /128
        conv_mfma_kernel<64, true, true, true><<<nblk, 256, 0, stream>>>(
            ans2b, f_off, fe_j, f_coeff, Wp3, bias3, ans2b, d_out, NF);
    } else {
        conv_layer_kernel<96, false, false, false, true><<<NF, 256, 0, stream>>>(
            A1b, W[4], bb[4], W[5], bb[5], fcW1, fcb1, f_off, fe_j, f_coeff, ans2b);
        conv_layer_kernel<64, true, true, true, false><<<NF, 256, 0, stream>>>(
            ans2b, W[6], bb[6], W[7], bb[7], fcW2, fcb2, f_off, fe_j, f_coeff, d_out);
    }
}

// Round 13
// 100.511 us; speedup vs baseline: 2.7357x; 1.2243x over previous
//
#include <hip/hip_runtime.h>
#include <math.h>

#define SUPPORT 1.5f

typedef unsigned short ushort_t;
typedef short bf16x8 __attribute__((ext_vector_type(8)));
typedef float f32x4 __attribute__((ext_vector_type(4)));

__device__ __forceinline__ float bf2f(unsigned short h) {
    union { unsigned int u; float f; } c;
    c.u = ((unsigned int)h) << 16;
    return c.f;
}
__device__ __forceinline__ unsigned short f2bf(float f) {
    union { float f; unsigned int u; } c;
    c.f = f;
    unsigned int lsb = (c.u >> 16) & 1u;
    c.u += 0x7fffu + lsb;   // round-to-nearest-even
    return (unsigned short)(c.u >> 16);
}

__device__ __forceinline__ void hat4(float u, float h[4]) {
#pragma unroll
    for (int j = 0; j < 4; ++j) {
        float c = -1.0f + j * (2.0f / 3.0f);
        h[j] = fmaxf(0.0f, 1.0f - fabsf(u - c) * 1.5f);
    }
}

__device__ __forceinline__ void coeff16(float2 A, float2 B, bool neg, float* o) {
    float rx = (A.x - B.x) / SUPPORT;
    float ry = (A.y - B.y) / SUPPORT;
    if (neg) { rx = -rx; ry = -ry; }
    float dx = fminf(fmaxf(rx, -1.0f), 1.0f);
    float dy = fminf(fmaxf(ry, -1.0f), 1.0f);
    float r  = sqrtf(dx * dx + dy * dy) * 2.0f - 1.0f;
    float th = atan2f(dy, dx) / 3.14159265358979323846f;
    float hr[4], ht[4];
    hat4(r, hr);
    hat4(th, ht);
#pragma unroll
    for (int a = 0; a < 4; ++a)
#pragma unroll
        for (int b = 0; b < 4; ++b)
            o[a * 4 + b] = hr[a] * ht[b];
}

__device__ __forceinline__ int lower_bound(const int* __restrict__ arr, int E, int key) {
    int lo = 0, hi = E;
    while (lo < hi) {
        int mid = (lo + hi) >> 1;
        if (arr[mid] < key) lo = mid + 1; else hi = mid;
    }
    return lo;
}

__device__ __forceinline__ void packW(const float* __restrict__ WA,
                                      const float* __restrict__ WB,
                                      const float* __restrict__ fcW,
                                      ushort_t* __restrict__ Wp, int CIN, int idx) {
    int j8   = idx & 7;
    int lane = (idx >> 3) & 63;
    int tile = (idx >> 9) & 3;
    int ks   = idx >> 11;
    int kk = ks * 32 + ((lane >> 4) << 3) + j8;
    int o  = tile * 16 + (lane & 15);
    int KC = 16 * CIN;
    float v = (kk < KC) ? ((o < 32) ? WA[(size_t)kk * 32 + o] : WB[(size_t)kk * 32 + (o - 32)])
                        : fcW[(size_t)(kk - KC) * 64 + o];
    Wp[idx] = f2bf(v);
}

// ---------------- fused prologue: coeffs + CSR offsets + W packing + biases ----------------
__global__ void prologue_kernel(
    const float2* __restrict__ fPos, const float2* __restrict__ bPos,
    const int* __restrict__ fe_i, const int* __restrict__ fe_j,
    const int* __restrict__ be_f, const int* __restrict__ be_b,
    const float* __restrict__ W4, const float* __restrict__ W5,
    const float* __restrict__ fcW1, const float* __restrict__ b4,
    const float* __restrict__ b5, const float* __restrict__ fcb1,
    const float* __restrict__ W6, const float* __restrict__ W7,
    const float* __restrict__ fcW2, const float* __restrict__ b6,
    const float* __restrict__ b7, const float* __restrict__ fcb2,
    float* __restrict__ f_coeff, float* __restrict__ b_coeff,
    int* __restrict__ f_off, int* __restrict__ b_off,
    ushort_t* __restrict__ Wp2, float* __restrict__ bias2,
    ushort_t* __restrict__ Wp3, float* __restrict__ bias3,
    int EF, int EB, int NF) {
    int idx = blockIdx.x * 256 + threadIdx.x;
    if (idx < EF) {
        float co[16];
        coeff16(fPos[fe_j[idx]], fPos[fe_i[idx]], true, co);
        float* o = f_coeff + (size_t)idx * 16;
#pragma unroll
        for (int i = 0; i < 16; ++i) o[i] = co[i];
        return;
    }
    idx -= EF;
    if (idx < EB) {
        float co[16];
        coeff16(bPos[be_b[idx]], fPos[be_f[idx]], false, co);
        float* o = b_coeff + (size_t)idx * 16;
#pragma unroll
        for (int i = 0; i < 16; ++i) o[i] = co[i];
        return;
    }
    idx -= EB;
    if (idx < NF + 1) { f_off[idx] = lower_bound(fe_i, EF, idx); return; }
    idx -= NF + 1;
    if (idx < NF + 1) { b_off[idx] = lower_bound(be_f, EB, idx); return; }
    idx -= NF + 1;
    if (idx < 64) { bias2[idx] = ((idx < 32) ? b4[idx] : b5[idx - 32]) + fcb1[idx]; return; }
    idx -= 64;
    if (idx < 51 * 2048) { packW(W4, W5, fcW1, Wp2, 96, idx); return; }
    idx -= 51 * 2048;
    if (idx < 64) { bias3[idx] = ((idx < 32) ? b6[idx] : b7[idx - 32]) + fcb2[idx]; return; }
    idx -= 64;
    if (idx < 34 * 2048) { packW(W6, W7, fcW2, Wp3, 64, idx); return; }
}

// ---------------- layer 1 (small Cin, direct); W columns hoisted ----------------
__global__ void layer1_kernel(const float* __restrict__ fluidFeats,
                              const float* __restrict__ boundaryFeats,
                              const float* __restrict__ fcW0, const float* __restrict__ fcb0,
                              const float* __restrict__ W0, const float* __restrict__ b0,
                              const float* __restrict__ W1, const float* __restrict__ b1,
                              const float* __restrict__ W2, const float* __restrict__ b2,
                              const float* __restrict__ W3, const float* __restrict__ b3,
                              const int* __restrict__ f_off, const int* __restrict__ fe_j,
                              const float* __restrict__ f_coeff,
                              const int* __restrict__ b_off, const int* __restrict__ be_b,
                              const float* __restrict__ b_coeff,
                              ushort_t* __restrict__ A1b) {
    int n = blockIdx.x;
    int t = threadIdx.x;
    if (t >= 96) return;
    float val;
    if (t < 32) {
        val = fluidFeats[n * 2] * fcW0[t] + fluidFeats[n * 2 + 1] * fcW0[32 + t] + fcb0[t];
    } else if (t < 64) {
        int oc = t - 32;
        const float* W = (oc < 16) ? W0 : W1;
        int o16 = oc & 15;
        float wk[32];
#pragma unroll
        for (int k = 0; k < 16; ++k) {
            wk[2 * k + 0] = W[(k * 2 + 0) * 16 + o16];
            wk[2 * k + 1] = W[(k * 2 + 1) * 16 + o16];
        }
        float s = (oc < 16) ? b0[o16] : b1[o16];
        int e1 = f_off[n + 1];
        for (int e = f_off[n]; e < e1; ++e) {
            const float* cf = f_coeff + (size_t)e * 16;
            int srcn = fe_j[e];
            float f0 = fluidFeats[srcn * 2], f1 = fluidFeats[srcn * 2 + 1];
            float acc = 0.0f;
#pragma unroll
            for (int k = 0; k < 16; ++k)
                acc += cf[k] * (f0 * wk[2 * k] + f1 * wk[2 * k + 1]);
            s += acc;
        }
        val = s;
    } else {
        int oc = t - 64;
        const float* W = (oc < 16) ? W2 : W3;
        int o16 = oc & 15;
        float wk[48];
#pragma unroll
        for (int k = 0; k < 16; ++k) {
            wk[3 * k + 0] = W[(k * 3 + 0) * 16 + o16];
            wk[3 * k + 1] = W[(k * 3 + 1) * 16 + o16];
            wk[3 * k + 2] = W[(k * 3 + 2) * 16 + o16];
        }
        float s = (oc < 16) ? b2[o16] : b3[o16];
        int e1 = b_off[n + 1];
        for (int e = b_off[n]; e < e1; ++e) {
            const float* cf = b_coeff + (size_t)e * 16;
            int srcn = be_b[e];
            float f0 = boundaryFeats[srcn * 3], f1 = boundaryFeats[srcn * 3 + 1],
                  f2 = boundaryFeats[srcn * 3 + 2];
            float acc = 0.0f;
#pragma unroll
            for (int k = 0; k < 16; ++k)
                acc += cf[k] * (f0 * wk[3 * k] + f1 * wk[3 * k + 1] + f2 * wk[3 * k + 2]);
            s += acc;
        }
        val = s;
    }
    A1b[(size_t)n * 96 + t] = f2bf(fmaxf(val, 0.0f));
}

// ---------------- fused conv: buildG(LDS) + MFMA + epilogue; 8 waves / 16 nodes ----------------
// Wave wv builds nodes {2wv, 2wv+1}; phase 2: out-tile ot=wv&3, K-half kh=wv>>2 (ks += 2),
// then kh=1 waves dump partials to LDS and kh=0 waves reduce + epilogue.
template <int CIN, bool RELU, bool RESID, bool FINAL>
__global__ __launch_bounds__(512, 4) void conv_mfma_kernel(
    const ushort_t* __restrict__ Xb,
    const int* __restrict__ f_off, const int* __restrict__ fe_j,
    const float* __restrict__ f_coeff,
    const ushort_t* __restrict__ Wp, const float* __restrict__ bias,
    const ushort_t* __restrict__ XresB,
    void* __restrict__ OUT, int NF) {
    constexpr int KTOT   = 17 * CIN;        // 1632 or 1088
    constexpr int KSTEPS = KTOT / 32;       // 51 or 34
    constexpr int STRIDE = KTOT + 8;
    constexpr int EPT = CIN / 4;            // 24 or 16 bf16 per lane
    constexpr int NU4 = EPT / 8;            // 3 or 2

    __shared__ ushort_t Gl[16 * STRIDE];
    __shared__ float red[4][64][4];

    const int t = threadIdx.x;
    const int wv = t >> 6;
    const int lane = t & 63;
    const int nb = blockIdx.x * 16;

    // ---- phase 1: build G rows (wave-per-node, 2 nodes per wave) ----
    const int k  = lane >> 2;
    const int i0 = (lane & 3) * EPT;
    for (int s2 = 0; s2 < 2; ++s2) {
        int lnode = wv * 2 + s2;
        int n = nb + lnode;
        if (n > NF - 1) n = NF - 1;

        float acc[EPT];
#pragma unroll
        for (int s = 0; s < EPT; ++s) acc[s] = 0.0f;

        int e0 = f_off[n], e1 = f_off[n + 1];
        for (int e = e0; e < e1; e += 4) {
            int ea = e;
            int eb = (e + 1 < e1) ? e + 1 : e;
            int ec = (e + 2 < e1) ? e + 2 : e;
            int ed = (e + 3 < e1) ? e + 3 : e;
            int s0 = fe_j[ea], s1 = fe_j[eb], s2i = fe_j[ec], s3 = fe_j[ed];
            float c0 = f_coeff[(size_t)ea * 16 + k];
            float c1 = f_coeff[(size_t)eb * 16 + k];
            float c2 = f_coeff[(size_t)ec * 16 + k];
            float c3 = f_coeff[(size_t)ed * 16 + k];
            c1 = (e + 1 < e1) ? c1 : 0.0f;
            c2 = (e + 2 < e1) ? c2 : 0.0f;
            c3 = (e + 3 < e1) ? c3 : 0.0f;
            const uint4* x0 = (const uint4*)(Xb + (size_t)s0 * CIN + i0);
            const uint4* x1 = (const uint4*)(Xb + (size_t)s1 * CIN + i0);
            const uint4* x2 = (const uint4*)(Xb + (size_t)s2i * CIN + i0);
            const uint4* x3 = (const uint4*)(Xb + (size_t)s3 * CIN + i0);
            uint4 r0[NU4], r1[NU4], r2[NU4], r3[NU4];
#pragma unroll
            for (int q = 0; q < NU4; ++q) r0[q] = x0[q];
#pragma unroll
            for (int q = 0; q < NU4; ++q) r1[q] = x1[q];
#pragma unroll
            for (int q = 0; q < NU4; ++q) r2[q] = x2[q];
#pragma unroll
            for (int q = 0; q < NU4; ++q) r3[q] = x3[q];
#pragma unroll
            for (int q = 0; q < NU4; ++q) {
                unsigned int w0[4] = {r0[q].x, r0[q].y, r0[q].z, r0[q].w};
                unsigned int w1[4] = {r1[q].x, r1[q].y, r1[q].z, r1[q].w};
                unsigned int w2[4] = {r2[q].x, r2[q].y, r2[q].z, r2[q].w};
                unsigned int w3[4] = {r3[q].x, r3[q].y, r3[q].z, r3[q].w};
#pragma unroll
                for (int j = 0; j < 4; ++j) {
                    int s = q * 8 + j * 2;
#define EDGEFMA(wj, cc)                                                        \
                    {                                                          \
                        float lo = bf2f((unsigned short)(wj[j] & 0xffff));     \
                        float hi = bf2f((unsigned short)(wj[j] >> 16));        \
                        if (RELU) { lo = fmaxf(lo, 0.f); hi = fmaxf(hi, 0.f); }\
                        acc[s + 0] = fmaf(cc, lo, acc[s + 0]);                 \
                        acc[s + 1] = fmaf(cc, hi, acc[s + 1]);                 \
                    }
                    EDGEFMA(w0, c0)
                    EDGEFMA(w1, c1)
                    EDGEFMA(w2, c2)
                    EDGEFMA(w3, c3)
#undef EDGEFMA
                }
            }
        }

        ushort_t* grow = Gl + lnode * STRIDE;
        ushort_t* gp = grow + k * CIN + i0;
#pragma unroll
        for (int q = 0; q < NU4; ++q) {
            uint4 o;
            o.x = (unsigned int)f2bf(acc[q*8+0]) | ((unsigned int)f2bf(acc[q*8+1]) << 16);
            o.y = (unsigned int)f2bf(acc[q*8+2]) | ((unsigned int)f2bf(acc[q*8+3]) << 16);
            o.z = (unsigned int)f2bf(acc[q*8+4]) | ((unsigned int)f2bf(acc[q*8+5]) << 16);
            o.w = (unsigned int)f2bf(acc[q*8+6]) | ((unsigned int)f2bf(acc[q*8+7]) << 16);
            *(uint4*)(gp + q * 8) = o;
        }
        for (int i = lane; i < CIN; i += 64) {
            ushort_t v = Xb[(size_t)n * CIN + i];
            if (RELU && (v & 0x8000)) v = 0;
            grow[16 * CIN + i] = v;
        }
    }
    __syncthreads();

    // ---- phase 2: MFMA, K split across wave-pairs ----
    const int ot = wv & 3;
    const int kh = wv >> 2;
    f32x4 cacc = {0.f, 0.f, 0.f, 0.f};
    const ushort_t* garow = Gl + (lane & 15) * STRIDE + ((lane >> 4) << 3);
    const ushort_t* wpp = Wp + ((size_t)(ot * 64 + lane) << 3);
    for (int ks = kh; ks < KSTEPS; ks += 2) {
        bf16x8 a = *(const bf16x8*)(garow + ks * 32);
        bf16x8 b = *(const bf16x8*)(wpp + (size_t)ks * 2048);
        cacc = __builtin_amdgcn_mfma_f32_16x16x32_bf16(a, b, cacc, 0, 0, 0);
    }
    if (kh == 1) {
        red[ot][lane][0] = cacc[0];
        red[ot][lane][1] = cacc[1];
        red[ot][lane][2] = cacc[2];
        red[ot][lane][3] = cacc[3];
    }
    __syncthreads();
    if (kh == 0) {
        int o = ot * 16 + (lane & 15);
        float bo = bias[o];
#pragma unroll
        for (int r = 0; r < 4; ++r) {
            int node = nb + ((lane >> 4) << 2) + r;
            if (node < NF) {
                float s = cacc[r] + red[ot][lane][r] + bo;
                if (RESID) s += bf2f(XresB[(size_t)node * 64 + o]);
                if (FINAL) {
                    ((float*)OUT)[(size_t)node * 64 + o] = s * (1.0f / 128.0f);
                } else {
                    ((ushort_t*)OUT)[(size_t)node * 64 + o] = f2bf(s);
                }
            }
        }
    }
}

// ---------------- fallback path (bf16 X, fp32 W; proven) ----------------
template <int CIN, bool RELU_IN, bool RESIDUAL, bool FINAL, bool OUTBF>
__global__ __launch_bounds__(256) void conv_layer_kernel(
    const ushort_t* __restrict__ Xb,
    const float* __restrict__ WA, const float* __restrict__ bA,
    const float* __restrict__ WB, const float* __restrict__ bB,
    const float* __restrict__ fcW, const float* __restrict__ fcb,
    const int* __restrict__ f_off, const int* __restrict__ fe_j,
    const float* __restrict__ f_coeff,
    void* __restrict__ OUT) {
    constexpr int NELEM = 16 * CIN;
    constexpr int EPT = NELEM / 256;
    constexpr int BATCH = 8;
    constexpr int CHUNK = NELEM / 4;

    __shared__ float x_lds[CIN];
    __shared__ float feat[BATCH][CIN];
    __shared__ float co[BATCH][16];
    __shared__ float Gs[NELEM];
    __shared__ float red[4][64];

    int n = blockIdx.x;
    int t = threadIdx.x;

    for (int i = t; i < CIN; i += 256) {
        float v = bf2f(Xb[(size_t)n * CIN + i]);
        if (RELU_IN) v = fmaxf(v, 0.0f);
        x_lds[i] = v;
    }

    float acc[EPT];
    int kk[EPT], ii[EPT];
#pragma unroll
    for (int s = 0; s < EPT; ++s) {
        acc[s] = 0.0f;
        int j = s * 256 + t;
        kk[s] = j / CIN;
        ii[s] = j - kk[s] * CIN;
    }

    int e0 = f_off[n], e1 = f_off[n + 1];
    for (int eb = e0; eb < e1; eb += BATCH) {
        int cnt = min(BATCH, e1 - eb);
        __syncthreads();
        for (int idx = t; idx < cnt * 16; idx += 256) {
            int b = idx >> 4, c = idx & 15;
            co[b][c] = f_coeff[(size_t)(eb + b) * 16 + c];
        }
        for (int idx = t; idx < cnt * CIN; idx += 256) {
            int b = idx / CIN, i = idx - b * CIN;
            int srcn = fe_j[eb + b];
            float v = bf2f(Xb[(size_t)srcn * CIN + i]);
            if (RELU_IN) v = fmaxf(v, 0.0f);
            feat[b][i] = v;
        }
        __syncthreads();
#pragma unroll
        for (int b = 0; b < BATCH; ++b) {
            if (b >= cnt) break;
#pragma unroll
            for (int s = 0; s < EPT; ++s) acc[s] += co[b][kk[s]] * feat[b][ii[s]];
        }
    }
    __syncthreads();
#pragma unroll
    for (int s = 0; s < EPT; ++s) Gs[s * 256 + t] = acc[s];
    __syncthreads();

    int o = t & 63;
    int chunk = t >> 6;
    const float* Wp = (o < 32) ? WA : WB;
    int oc = o & 31;
    int j0 = chunk * CHUNK;
    float p0 = 0.f, p1 = 0.f, p2 = 0.f, p3 = 0.f;
    for (int j = j0; j < j0 + CHUNK; j += 4) {
        p0 += Gs[j + 0] * Wp[(size_t)(j + 0) * 32 + oc];
        p1 += Gs[j + 1] * Wp[(size_t)(j + 1) * 32 + oc];
        p2 += Gs[j + 2] * Wp[(size_t)(j + 2) * 32 + oc];
        p3 += Gs[j + 3] * Wp[(size_t)(j + 3) * 32 + oc];
    }
    red[chunk][o] = ((p0 + p1) + (p2 + p3));
    __syncthreads();
    if (t < 64) {
        float s = red[0][o] + red[1][o] + red[2][o] + red[3][o];
        s += (o < 32) ? bA[oc] : bB[oc];
        float fcv = fcb[o];
        for (int i = 0; i < CIN; ++i) fcv += x_lds[i] * fcW[i * 64 + o];
        s += fcv;
        if (RESIDUAL) s += bf2f(Xb[(size_t)n * 64 + o]);
        if (FINAL) s *= (1.0f / 128.0f);
        if (OUTBF) ((ushort_t*)OUT)[(size_t)n * 64 + o] = f2bf(s);
        else       ((float*)OUT)[(size_t)n * 64 + o] = s;
    }
}

extern "C" void kernel_launch(void* const* d_in, const int* in_sizes, int n_in,
                              void* d_out, int out_size, void* d_ws, size_t ws_size,
                              hipStream_t stream) {
    const float* fluidPos      = (const float*)d_in[0];
    const float* boundaryPos   = (const float*)d_in[1];
    const float* fluidFeats    = (const float*)d_in[2];
    const float* boundaryFeats = (const float*)d_in[3];
    const int* fe_i = (const int*)d_in[4];
    const int* fe_j = (const int*)d_in[5];
    const int* be_f = (const int*)d_in[6];
    const int* be_b = (const int*)d_in[7];
    const float* W[8];
    const float* bb[8];
    for (int c = 0; c < 8; ++c) {
        W[c]  = (const float*)d_in[8 + 2 * c];
        bb[c] = (const float*)d_in[9 + 2 * c];
    }
    const float* fcW0 = (const float*)d_in[24];
    const float* fcb0 = (const float*)d_in[25];
    const float* fcW1 = (const float*)d_in[26];
    const float* fcb1 = (const float*)d_in[27];
    const float* fcW2 = (const float*)d_in[28];
    const float* fcb2 = (const float*)d_in[29];

    int NF = in_sizes[0] / 2;
    int EF = in_sizes[4];
    int EB = in_sizes[6];

    // ---- workspace layout (f32 units) ----
    float* ws = (float*)d_ws;
    size_t p = 0;
    float* f_coeff = ws + p;  p += (size_t)EF * 16;
    float* b_coeff = ws + p;  p += (size_t)EB * 16;
    ushort_t* A1b  = (ushort_t*)(ws + p);  p += (size_t)NF * 48;   // NF*96 bf16
    ushort_t* ans2b= (ushort_t*)(ws + p);  p += (size_t)NF * 32;   // NF*64 bf16
    int*   f_off   = (int*)(ws + p);  p += (size_t)((NF + 4) & ~3);
    int*   b_off   = (int*)(ws + p);  p += (size_t)((NF + 4) & ~3);
    ushort_t* Wp2  = (ushort_t*)(ws + p);  p += 1632 * 32;   // 1632*64 bf16
    float* bias2   = ws + p;  p += 64;
    ushort_t* Wp3  = (ushort_t*)(ws + p);  p += 1088 * 32;
    float* bias3   = ws + p;  p += 64;

    bool bigPath = (ws_size / 4 >= p);

    int totalPro = EF + EB + 2 * (NF + 1) + 64 + 51 * 2048 + 64 + 34 * 2048;
    prologue_kernel<<<(totalPro + 255) / 256, 256, 0, stream>>>(
        (const float2*)fluidPos, (const float2*)boundaryPos,
        fe_i, fe_j, be_f, be_b,
        W[4], W[5], fcW1, bb[4], bb[5], fcb1,
        W[6], W[7], fcW2, bb[6], bb[7], fcb2,
        f_coeff, b_coeff, f_off, b_off,
        Wp2, bias2, Wp3, bias3, EF, EB, NF);

    layer1_kernel<<<NF, 128, 0, stream>>>(fluidFeats, boundaryFeats, fcW0, fcb0,
                                          W[0], bb[0], W[1], bb[1], W[2], bb[2], W[3], bb[3],
                                          f_off, fe_j, f_coeff, b_off, be_b, b_coeff, A1b);

    if (bigPath) {
        int nblk = (NF + 15) / 16;
        conv_mfma_kernel<96, false, false, false><<<nblk, 512, 0, stream>>>(
            A1b, f_off, fe_j, f_coeff, Wp2, bias2, nullptr, ans2b, NF);
        conv_mfma_kernel<64, true, true, true><<<nblk, 512, 0, stream>>>(
            ans2b, f_off, fe_j, f_coeff, Wp3, bias3, ans2b, d_out, NF);
    } else {
        conv_layer_kernel<96, false, false, false, true><<<NF, 256, 0, stream>>>(
            A1b, W[4], bb[4], W[5], bb[5], fcW1, fcb1, f_off, fe_j, f_coeff, ans2b);
        conv_layer_kernel<64, true, true, true, false><<<NF, 256, 0, stream>>>(
            ans2b, W[6], bb[6], W[7], bb[7], fcW2, fcb2, f_off, fe_j, f_coeff, d_out);
    }
}

// Round 14
// 98.247 us; speedup vs baseline: 2.7987x; 1.0230x over previous
//
#include <hip/hip_runtime.h>
#include <math.h>

#define SUPPORT 1.5f

typedef unsigned short ushort_t;
typedef short bf16x8 __attribute__((ext_vector_type(8)));
typedef float f32x4 __attribute__((ext_vector_type(4)));

__device__ __forceinline__ float bf2f(unsigned short h) {
    union { unsigned int u; float f; } c;
    c.u = ((unsigned int)h) << 16;
    return c.f;
}
__device__ __forceinline__ unsigned short f2bf(float f) {
    union { float f; unsigned int u; } c;
    c.f = f;
    unsigned int lsb = (c.u >> 16) & 1u;
    c.u += 0x7fffu + lsb;   // round-to-nearest-even
    return (unsigned short)(c.u >> 16);
}

__device__ __forceinline__ void hat4(float u, float h[4]) {
#pragma unroll
    for (int j = 0; j < 4; ++j) {
        float c = -1.0f + j * (2.0f / 3.0f);
        h[j] = fmaxf(0.0f, 1.0f - fabsf(u - c) * 1.5f);
    }
}

__device__ __forceinline__ void coeff16(float2 A, float2 B, bool neg, float* o) {
    float rx = (A.x - B.x) / SUPPORT;
    float ry = (A.y - B.y) / SUPPORT;
    if (neg) { rx = -rx; ry = -ry; }
    float dx = fminf(fmaxf(rx, -1.0f), 1.0f);
    float dy = fminf(fmaxf(ry, -1.0f), 1.0f);
    float r  = sqrtf(dx * dx + dy * dy) * 2.0f - 1.0f;
    float th = atan2f(dy, dx) / 3.14159265358979323846f;
    float hr[4], ht[4];
    hat4(r, hr);
    hat4(th, ht);
#pragma unroll
    for (int a = 0; a < 4; ++a)
#pragma unroll
        for (int b = 0; b < 4; ++b)
            o[a * 4 + b] = hr[a] * ht[b];
}

__device__ __forceinline__ int lower_bound(const int* __restrict__ arr, int E, int key) {
    int lo = 0, hi = E;
    while (lo < hi) {
        int mid = (lo + hi) >> 1;
        if (arr[mid] < key) lo = mid + 1; else hi = mid;
    }
    return lo;
}

__device__ __forceinline__ void packW(const float* __restrict__ WA,
                                      const float* __restrict__ WB,
                                      const float* __restrict__ fcW,
                                      ushort_t* __restrict__ Wp, int CIN, int idx) {
    int j8   = idx & 7;
    int lane = (idx >> 3) & 63;
    int tile = (idx >> 9) & 3;
    int ks   = idx >> 11;
    int kk = ks * 32 + ((lane >> 4) << 3) + j8;
    int o  = tile * 16 + (lane & 15);
    int KC = 16 * CIN;
    float v = (kk < KC) ? ((o < 32) ? WA[(size_t)kk * 32 + o] : WB[(size_t)kk * 32 + (o - 32)])
                        : fcW[(size_t)(kk - KC) * 64 + o];
    Wp[idx] = f2bf(v);
}

// ---------------- fused prologue: coeffs + CSR offsets + W packing + biases ----------------
__global__ void prologue_kernel(
    const float2* __restrict__ fPos, const float2* __restrict__ bPos,
    const int* __restrict__ fe_i, const int* __restrict__ fe_j,
    const int* __restrict__ be_f, const int* __restrict__ be_b,
    const float* __restrict__ W4, const float* __restrict__ W5,
    const float* __restrict__ fcW1, const float* __restrict__ b4,
    const float* __restrict__ b5, const float* __restrict__ fcb1,
    const float* __restrict__ W6, const float* __restrict__ W7,
    const float* __restrict__ fcW2, const float* __restrict__ b6,
    const float* __restrict__ b7, const float* __restrict__ fcb2,
    float* __restrict__ f_coeff, float* __restrict__ b_coeff,
    int* __restrict__ f_off, int* __restrict__ b_off,
    ushort_t* __restrict__ Wp2, float* __restrict__ bias2,
    ushort_t* __restrict__ Wp3, float* __restrict__ bias3,
    int EF, int EB, int NF) {
    int idx = blockIdx.x * 256 + threadIdx.x;
    if (idx < EF) {
        float co[16];
        coeff16(fPos[fe_j[idx]], fPos[fe_i[idx]], true, co);
        float* o = f_coeff + (size_t)idx * 16;
#pragma unroll
        for (int i = 0; i < 16; ++i) o[i] = co[i];
        return;
    }
    idx -= EF;
    if (idx < EB) {
        float co[16];
        coeff16(bPos[be_b[idx]], fPos[be_f[idx]], false, co);
        float* o = b_coeff + (size_t)idx * 16;
#pragma unroll
        for (int i = 0; i < 16; ++i) o[i] = co[i];
        return;
    }
    idx -= EB;
    if (idx < NF + 1) { f_off[idx] = lower_bound(fe_i, EF, idx); return; }
    idx -= NF + 1;
    if (idx < NF + 1) { b_off[idx] = lower_bound(be_f, EB, idx); return; }
    idx -= NF + 1;
    if (idx < 64) { bias2[idx] = ((idx < 32) ? b4[idx] : b5[idx - 32]) + fcb1[idx]; return; }
    idx -= 64;
    if (idx < 51 * 2048) { packW(W4, W5, fcW1, Wp2, 96, idx); return; }
    idx -= 51 * 2048;
    if (idx < 64) { bias3[idx] = ((idx < 32) ? b6[idx] : b7[idx - 32]) + fcb2[idx]; return; }
    idx -= 64;
    if (idx < 34 * 2048) { packW(W6, W7, fcW2, Wp3, 64, idx); return; }
}

// ---------------- layer 1: 4-wide masked edge unroll, W columns hoisted ----------------
__global__ void layer1_kernel(const float* __restrict__ fluidFeats,
                              const float* __restrict__ boundaryFeats,
                              const float* __restrict__ fcW0, const float* __restrict__ fcb0,
                              const float* __restrict__ W0, const float* __restrict__ b0,
                              const float* __restrict__ W1, const float* __restrict__ b1,
                              const float* __restrict__ W2, const float* __restrict__ b2,
                              const float* __restrict__ W3, const float* __restrict__ b3,
                              const int* __restrict__ f_off, const int* __restrict__ fe_j,
                              const float* __restrict__ f_coeff,
                              const int* __restrict__ b_off, const int* __restrict__ be_b,
                              const float* __restrict__ b_coeff,
                              ushort_t* __restrict__ A1b) {
    int n = blockIdx.x;
    int t = threadIdx.x;
    if (t >= 96) return;
    float val;
    if (t < 32) {
        val = fluidFeats[n * 2] * fcW0[t] + fluidFeats[n * 2 + 1] * fcW0[32 + t] + fcb0[t];
    } else if (t < 64) {
        int oc = t - 32;
        const float* W = (oc < 16) ? W0 : W1;
        int o16 = oc & 15;
        float wk[32];
#pragma unroll
        for (int k = 0; k < 16; ++k) {
            wk[2 * k + 0] = W[(k * 2 + 0) * 16 + o16];
            wk[2 * k + 1] = W[(k * 2 + 1) * 16 + o16];
        }
        float s = (oc < 16) ? b0[o16] : b1[o16];
        int e0 = f_off[n], e1 = f_off[n + 1];
        for (int e = e0; e < e1; e += 4) {
            int ee[4];
            float msk[4];
#pragma unroll
            for (int u = 0; u < 4; ++u) {
                ee[u] = (e + u < e1) ? e + u : e;
                msk[u] = (e + u < e1) ? 1.0f : 0.0f;
            }
            int sn[4];
#pragma unroll
            for (int u = 0; u < 4; ++u) sn[u] = fe_j[ee[u]];
            float4 c4[4][4];
#pragma unroll
            for (int u = 0; u < 4; ++u) {
                const float4* cf4 = (const float4*)(f_coeff + (size_t)ee[u] * 16);
#pragma unroll
                for (int q = 0; q < 4; ++q) c4[u][q] = cf4[q];
            }
            float2 fv[4];
#pragma unroll
            for (int u = 0; u < 4; ++u)
                fv[u] = *(const float2*)(fluidFeats + (size_t)sn[u] * 2);
#pragma unroll
            for (int u = 0; u < 4; ++u) {
                float f0 = fv[u].x * msk[u], f1 = fv[u].y * msk[u];
                const float* cf = (const float*)&c4[u][0];
                float acc = 0.0f;
#pragma unroll
                for (int k = 0; k < 16; ++k)
                    acc += cf[k] * (f0 * wk[2 * k] + f1 * wk[2 * k + 1]);
                s += acc;
            }
        }
        val = s;
    } else {
        int oc = t - 64;
        const float* W = (oc < 16) ? W2 : W3;
        int o16 = oc & 15;
        float wk[48];
#pragma unroll
        for (int k = 0; k < 16; ++k) {
            wk[3 * k + 0] = W[(k * 3 + 0) * 16 + o16];
            wk[3 * k + 1] = W[(k * 3 + 1) * 16 + o16];
            wk[3 * k + 2] = W[(k * 3 + 2) * 16 + o16];
        }
        float s = (oc < 16) ? b2[o16] : b3[o16];
        int e0 = b_off[n], e1 = b_off[n + 1];
        for (int e = e0; e < e1; e += 4) {
            int ee[4];
            float msk[4];
#pragma unroll
            for (int u = 0; u < 4; ++u) {
                ee[u] = (e + u < e1) ? e + u : e;
                msk[u] = (e + u < e1) ? 1.0f : 0.0f;
            }
            int sn[4];
#pragma unroll
            for (int u = 0; u < 4; ++u) sn[u] = be_b[ee[u]];
            float4 c4[4][4];
#pragma unroll
            for (int u = 0; u < 4; ++u) {
                const float4* cf4 = (const float4*)(b_coeff + (size_t)ee[u] * 16);
#pragma unroll
                for (int q = 0; q < 4; ++q) c4[u][q] = cf4[q];
            }
            float bf[4][3];
#pragma unroll
            for (int u = 0; u < 4; ++u) {
                bf[u][0] = boundaryFeats[(size_t)sn[u] * 3 + 0];
                bf[u][1] = boundaryFeats[(size_t)sn[u] * 3 + 1];
                bf[u][2] = boundaryFeats[(size_t)sn[u] * 3 + 2];
            }
#pragma unroll
            for (int u = 0; u < 4; ++u) {
                float f0 = bf[u][0] * msk[u], f1 = bf[u][1] * msk[u], f2 = bf[u][2] * msk[u];
                const float* cf = (const float*)&c4[u][0];
                float acc = 0.0f;
#pragma unroll
                for (int k = 0; k < 16; ++k)
                    acc += cf[k] * (f0 * wk[3 * k] + f1 * wk[3 * k + 1] + f2 * wk[3 * k + 2]);
                s += acc;
            }
        }
        val = s;
    }
    A1b[(size_t)n * 96 + t] = f2bf(fmaxf(val, 0.0f));
}

// ---------------- fused conv: buildG(LDS) + MFMA + epilogue; 8 waves / 16 nodes ----------------
template <int CIN, bool RELU, bool RESID, bool FINAL>
__global__ __launch_bounds__(512, 4) void conv_mfma_kernel(
    const ushort_t* __restrict__ Xb,
    const int* __restrict__ f_off, const int* __restrict__ fe_j,
    const float* __restrict__ f_coeff,
    const ushort_t* __restrict__ Wp, const float* __restrict__ bias,
    const ushort_t* __restrict__ XresB,
    void* __restrict__ OUT, int NF) {
    constexpr int KTOT   = 17 * CIN;        // 1632 or 1088
    constexpr int KSTEPS = KTOT / 32;       // 51 or 34
    constexpr int STRIDE = KTOT + 8;
    constexpr int EPT = CIN / 4;            // 24 or 16 bf16 per lane
    constexpr int NU4 = EPT / 8;            // 3 or 2

    __shared__ ushort_t Gl[16 * STRIDE];
    __shared__ float red[4][64][4];

    const int t = threadIdx.x;
    const int wv = t >> 6;
    const int lane = t & 63;
    const int nb = blockIdx.x * 16;

    const int k  = lane >> 2;
    const int i0 = (lane & 3) * EPT;
    for (int s2 = 0; s2 < 2; ++s2) {
        int lnode = wv * 2 + s2;
        int n = nb + lnode;
        if (n > NF - 1) n = NF - 1;

        float acc[EPT];
#pragma unroll
        for (int s = 0; s < EPT; ++s) acc[s] = 0.0f;

        int e0 = f_off[n], e1 = f_off[n + 1];
        for (int e = e0; e < e1; e += 4) {
            int ea = e;
            int eb = (e + 1 < e1) ? e + 1 : e;
            int ec = (e + 2 < e1) ? e + 2 : e;
            int ed = (e + 3 < e1) ? e + 3 : e;
            int s0 = fe_j[ea], s1 = fe_j[eb], s2i = fe_j[ec], s3 = fe_j[ed];
            float c0 = f_coeff[(size_t)ea * 16 + k];
            float c1 = f_coeff[(size_t)eb * 16 + k];
            float c2 = f_coeff[(size_t)ec * 16 + k];
            float c3 = f_coeff[(size_t)ed * 16 + k];
            c1 = (e + 1 < e1) ? c1 : 0.0f;
            c2 = (e + 2 < e1) ? c2 : 0.0f;
            c3 = (e + 3 < e1) ? c3 : 0.0f;
            const uint4* x0 = (const uint4*)(Xb + (size_t)s0 * CIN + i0);
            const uint4* x1 = (const uint4*)(Xb + (size_t)s1 * CIN + i0);
            const uint4* x2 = (const uint4*)(Xb + (size_t)s2i * CIN + i0);
            const uint4* x3 = (const uint4*)(Xb + (size_t)s3 * CIN + i0);
            uint4 r0[NU4], r1[NU4], r2[NU4], r3[NU4];
#pragma unroll
            for (int q = 0; q < NU4; ++q) r0[q] = x0[q];
#pragma unroll
            for (int q = 0; q < NU4; ++q) r1[q] = x1[q];
#pragma unroll
            for (int q = 0; q < NU4; ++q) r2[q] = x2[q];
#pragma unroll
            for (int q = 0; q < NU4; ++q) r3[q] = x3[q];
#pragma unroll
            for (int q = 0; q < NU4; ++q) {
                unsigned int w0[4] = {r0[q].x, r0[q].y, r0[q].z, r0[q].w};
                unsigned int w1[4] = {r1[q].x, r1[q].y, r1[q].z, r1[q].w};
                unsigned int w2[4] = {r2[q].x, r2[q].y, r2[q].z, r2[q].w};
                unsigned int w3[4] = {r3[q].x, r3[q].y, r3[q].z, r3[q].w};
#pragma unroll
                for (int j = 0; j < 4; ++j) {
                    int s = q * 8 + j * 2;
#define EDGEFMA(wj, cc)                                                        \
                    {                                                          \
                        float lo = bf2f((unsigned short)(wj[j] & 0xffff));     \
                        float hi = bf2f((unsigned short)(wj[j] >> 16));        \
                        if (RELU) { lo = fmaxf(lo, 0.f); hi = fmaxf(hi, 0.f); }\
                        acc[s + 0] = fmaf(cc, lo, acc[s + 0]);                 \
                        acc[s + 1] = fmaf(cc, hi, acc[s + 1]);                 \
                    }
                    EDGEFMA(w0, c0)
                    EDGEFMA(w1, c1)
                    EDGEFMA(w2, c2)
                    EDGEFMA(w3, c3)
#undef EDGEFMA
                }
            }
        }

        ushort_t* grow = Gl + lnode * STRIDE;
        ushort_t* gp = grow + k * CIN + i0;
#pragma unroll
        for (int q = 0; q < NU4; ++q) {
            uint4 o;
            o.x = (unsigned int)f2bf(acc[q*8+0]) | ((unsigned int)f2bf(acc[q*8+1]) << 16);
            o.y = (unsigned int)f2bf(acc[q*8+2]) | ((unsigned int)f2bf(acc[q*8+3]) << 16);
            o.z = (unsigned int)f2bf(acc[q*8+4]) | ((unsigned int)f2bf(acc[q*8+5]) << 16);
            o.w = (unsigned int)f2bf(acc[q*8+6]) | ((unsigned int)f2bf(acc[q*8+7]) << 16);
            *(uint4*)(gp + q * 8) = o;
        }
        for (int i = lane; i < CIN; i += 64) {
            ushort_t v = Xb[(size_t)n * CIN + i];
            if (RELU && (v & 0x8000)) v = 0;
            grow[16 * CIN + i] = v;
        }
    }
    __syncthreads();

    const int ot = wv & 3;
    const int kh = wv >> 2;
    f32x4 cacc = {0.f, 0.f, 0.f, 0.f};
    const ushort_t* garow = Gl + (lane & 15) * STRIDE + ((lane >> 4) << 3);
    const ushort_t* wpp = Wp + ((size_t)(ot * 64 + lane) << 3);
    for (int ks = kh; ks < KSTEPS; ks += 2) {
        bf16x8 a = *(const bf16x8*)(garow + ks * 32);
        bf16x8 b = *(const bf16x8*)(wpp + (size_t)ks * 2048);
        cacc = __builtin_amdgcn_mfma_f32_16x16x32_bf16(a, b, cacc, 0, 0, 0);
    }
    if (kh == 1) {
        red[ot][lane][0] = cacc[0];
        red[ot][lane][1] = cacc[1];
        red[ot][lane][2] = cacc[2];
        red[ot][lane][3] = cacc[3];
    }
    __syncthreads();
    if (kh == 0) {
        int o = ot * 16 + (lane & 15);
        float bo = bias[o];
#pragma unroll
        for (int r = 0; r < 4; ++r) {
            int node = nb + ((lane >> 4) << 2) + r;
            if (node < NF) {
                float s = cacc[r] + red[ot][lane][r] + bo;
                if (RESID) s += bf2f(XresB[(size_t)node * 64 + o]);
                if (FINAL) {
                    ((float*)OUT)[(size_t)node * 64 + o] = s * (1.0f / 128.0f);
                } else {
                    ((ushort_t*)OUT)[(size_t)node * 64 + o] = f2bf(s);
                }
            }
        }
    }
}

// ---------------- fallback path (bf16 X, fp32 W; proven) ----------------
template <int CIN, bool RELU_IN, bool RESIDUAL, bool FINAL, bool OUTBF>
__global__ __launch_bounds__(256) void conv_layer_kernel(
    const ushort_t* __restrict__ Xb,
    const float* __restrict__ WA, const float* __restrict__ bA,
    const float* __restrict__ WB, const float* __restrict__ bB,
    const float* __restrict__ fcW, const float* __restrict__ fcb,
    const int* __restrict__ f_off, const int* __restrict__ fe_j,
    const float* __restrict__ f_coeff,
    void* __restrict__ OUT) {
    constexpr int NELEM = 16 * CIN;
    constexpr int EPT = NELEM / 256;
    constexpr int BATCH = 8;
    constexpr int CHUNK = NELEM / 4;

    __shared__ float x_lds[CIN];
    __shared__ float feat[BATCH][CIN];
    __shared__ float co[BATCH][16];
    __shared__ float Gs[NELEM];
    __shared__ float red[4][64];

    int n = blockIdx.x;
    int t = threadIdx.x;

    for (int i = t; i < CIN; i += 256) {
        float v = bf2f(Xb[(size_t)n * CIN + i]);
        if (RELU_IN) v = fmaxf(v, 0.0f);
        x_lds[i] = v;
    }

    float acc[EPT];
    int kk[EPT], ii[EPT];
#pragma unroll
    for (int s = 0; s < EPT; ++s) {
        acc[s] = 0.0f;
        int j = s * 256 + t;
        kk[s] = j / CIN;
        ii[s] = j - kk[s] * CIN;
    }

    int e0 = f_off[n], e1 = f_off[n + 1];
    for (int eb = e0; eb < e1; eb += BATCH) {
        int cnt = min(BATCH, e1 - eb);
        __syncthreads();
        for (int idx = t; idx < cnt * 16; idx += 256) {
            int b = idx >> 4, c = idx & 15;
            co[b][c] = f_coeff[(size_t)(eb + b) * 16 + c];
        }
        for (int idx = t; idx < cnt * CIN; idx += 256) {
            int b = idx / CIN, i = idx - b * CIN;
            int srcn = fe_j[eb + b];
            float v = bf2f(Xb[(size_t)srcn * CIN + i]);
            if (RELU_IN) v = fmaxf(v, 0.0f);
            feat[b][i] = v;
        }
        __syncthreads();
#pragma unroll
        for (int b = 0; b < BATCH; ++b) {
            if (b >= cnt) break;
#pragma unroll
            for (int s = 0; s < EPT; ++s) acc[s] += co[b][kk[s]] * feat[b][ii[s]];
        }
    }
    __syncthreads();
#pragma unroll
    for (int s = 0; s < EPT; ++s) Gs[s * 256 + t] = acc[s];
    __syncthreads();

    int o = t & 63;
    int chunk = t >> 6;
    const float* Wp = (o < 32) ? WA : WB;
    int oc = o & 31;
    int j0 = chunk * CHUNK;
    float p0 = 0.f, p1 = 0.f, p2 = 0.f, p3 = 0.f;
    for (int j = j0; j < j0 + CHUNK; j += 4) {
        p0 += Gs[j + 0] * Wp[(size_t)(j + 0) * 32 + oc];
        p1 += Gs[j + 1] * Wp[(size_t)(j + 1) * 32 + oc];
        p2 += Gs[j + 2] * Wp[(size_t)(j + 2) * 32 + oc];
        p3 += Gs[j + 3] * Wp[(size_t)(j + 3) * 32 + oc];
    }
    red[chunk][o] = ((p0 + p1) + (p2 + p3));
    __syncthreads();
    if (t < 64) {
        float s = red[0][o] + red[1][o] + red[2][o] + red[3][o];
        s += (o < 32) ? bA[oc] : bB[oc];
        float fcv = fcb[o];
        for (int i = 0; i < CIN; ++i) fcv += x_lds[i] * fcW[i * 64 + o];
        s += fcv;
        if (RESIDUAL) s += bf2f(Xb[(size_t)n * 64 + o]);
        if (FINAL) s *= (1.0f / 128.0f);
        if (OUTBF) ((ushort_t*)OUT)[(size_t)n * 64 + o] = f2bf(s);
        else       ((float*)OUT)[(size_t)n * 64 + o] = s;
    }
}

extern "C" void kernel_launch(void* const* d_in, const int* in_sizes, int n_in,
                              void* d_out, int out_size, void* d_ws, size_t ws_size,
                              hipStream_t stream) {
    const float* fluidPos      = (const float*)d_in[0];
    const float* boundaryPos   = (const float*)d_in[1];
    const float* fluidFeats    = (const float*)d_in[2];
    const float* boundaryFeats = (const float*)d_in[3];
    const int* fe_i = (const int*)d_in[4];
    const int* fe_j = (const int*)d_in[5];
    const int* be_f = (const int*)d_in[6];
    const int* be_b = (const int*)d_in[7];
    const float* W[8];
    const float* bb[8];
    for (int c = 0; c < 8; ++c) {
        W[c]  = (const float*)d_in[8 + 2 * c];
        bb[c] = (const float*)d_in[9 + 2 * c];
    }
    const float* fcW0 = (const float*)d_in[24];
    const float* fcb0 = (const float*)d_in[25];
    const float* fcW1 = (const float*)d_in[26];
    const float* fcb1 = (const float*)d_in[27];
    const float* fcW2 = (const float*)d_in[28];
    const float* fcb2 = (const float*)d_in[29];

    int NF = in_sizes[0] / 2;
    int EF = in_sizes[4];
    int EB = in_sizes[6];

    // ---- workspace layout (f32 units) ----
    float* ws = (float*)d_ws;
    size_t p = 0;
    float* f_coeff = ws + p;  p += (size_t)EF * 16;
    float* b_coeff = ws + p;  p += (size_t)EB * 16;
    ushort_t* A1b  = (ushort_t*)(ws + p);  p += (size_t)NF * 48;   // NF*96 bf16
    ushort_t* ans2b= (ushort_t*)(ws + p);  p += (size_t)NF * 32;   // NF*64 bf16
    int*   f_off   = (int*)(ws + p);  p += (size_t)((NF + 4) & ~3);
    int*   b_off   = (int*)(ws + p);  p += (size_t)((NF + 4) & ~3);
    ushort_t* Wp2  = (ushort_t*)(ws + p);  p += 1632 * 32;   // 1632*64 bf16
    float* bias2   = ws + p;  p += 64;
    ushort_t* Wp3  = (ushort_t*)(ws + p);  p += 1088 * 32;
    float* bias3   = ws + p;  p += 64;

    bool bigPath = (ws_size / 4 >= p);

    int totalPro = EF + EB + 2 * (NF + 1) + 64 + 51 * 2048 + 64 + 34 * 2048;
    prologue_kernel<<<(totalPro + 255) / 256, 256, 0, stream>>>(
        (const float2*)fluidPos, (const float2*)boundaryPos,
        fe_i, fe_j, be_f, be_b,
        W[4], W[5], fcW1, bb[4], bb[5], fcb1,
        W[6], W[7], fcW2, bb[6], bb[7], fcb2,
        f_coeff, b_coeff, f_off, b_off,
        Wp2, bias2, Wp3, bias3, EF, EB, NF);

    layer1_kernel<<<NF, 128, 0, stream>>>(fluidFeats, boundaryFeats, fcW0, fcb0,
                                          W[0], bb[0], W[1], bb[1], W[2], bb[2], W[3], bb[3],
                                          f_off, fe_j, f_coeff, b_off, be_b, b_coeff, A1b);

    if (bigPath) {
        int nblk = (NF + 15) / 16;
        conv_mfma_kernel<96, false, false, false><<<nblk, 512, 0, stream>>>(
            A1b, f_off, fe_j, f_coeff, Wp2, bias2, nullptr, ans2b, NF);
        conv_mfma_kernel<64, true, true, true><<<nblk, 512, 0, stream>>>(
            ans2b, f_off, fe_j, f_coeff, Wp3, bias3, ans2b, d_out, NF);
    } else {
        conv_layer_kernel<96, false, false, false, true><<<NF, 256, 0, stream>>>(
            A1b, W[4], bb[4], W[5], bb[5], fcW1, fcb1, f_off, fe_j, f_coeff, ans2b);
        conv_layer_kernel<64, true, true, true, false><<<NF, 256, 0, stream>>>(
            ans2b, W[6], bb[6], W[7], bb[7], fcW2, fcb2, f_off, fe_j, f_coeff, d_out);
    }
}